// Round 4
// baseline (568.951 us; speedup 1.0000x reference)
//
#include <hip/hip_runtime.h>
#include <math.h>

#define N_NODES 50000
#define SEQ_LEN 32
#define EMB_DIM 128
#define IN_FEATS 256
#define N_HIDDEN 256
#define N_CLASSES 40
#define N_EDGES 800000
#define N_TOKENS 100000

constexpr int SCAN_CHUNK = 512;
constexpr int N_CHUNKS = (N_NODES + SCAN_CHUNK - 1) / SCAN_CHUNK; // 98

typedef short short8 __attribute__((ext_vector_type(8)));
typedef float f32x4 __attribute__((ext_vector_type(4)));

__device__ __forceinline__ unsigned short f2bf(float x) {
  unsigned int u = __float_as_uint(x);
  unsigned int r = (u + 0x7FFFu + ((u >> 16) & 1u)) >> 16; // RTNE
  return (unsigned short)r;
}
__device__ __forceinline__ float bf2f(unsigned short s) {
  return __uint_as_float((unsigned int)s << 16);
}
__device__ __forceinline__ unsigned int pack2bf(float a, float b) {
  return (unsigned int)f2bf(a) | ((unsigned int)f2bf(b) << 16);
}

// ---------------- degree / norms ----------------
__global__ __launch_bounds__(256) void k_degree(const int* __restrict__ src,
                                                const int* __restrict__ dst,
                                                int* __restrict__ deg_out,
                                                int* __restrict__ deg_in) {
  int e = blockIdx.x * 256 + threadIdx.x;
  if (e < N_EDGES) {
    atomicAdd(&deg_out[src[e]], 1);
    atomicAdd(&deg_in[dst[e]], 1);
  }
}

__global__ __launch_bounds__(256) void k_norm(const int* __restrict__ deg_out,
                                              const int* __restrict__ deg_in,
                                              float* __restrict__ norm_s,
                                              float* __restrict__ norm_d) {
  int i = blockIdx.x * 256 + threadIdx.x;
  if (i < N_NODES) {
    norm_s[i] = 1.0f / sqrtf((float)max(deg_out[i], 1));
    norm_d[i] = 1.0f / sqrtf((float)max(deg_in[i], 1));
  }
}

// ---------------- scan ----------------
__global__ __launch_bounds__(SCAN_CHUNK) void k_chunksum(const int* __restrict__ deg,
                                                         int* __restrict__ sums) {
  __shared__ int s[SCAN_CHUNK];
  int i = blockIdx.x * SCAN_CHUNK + threadIdx.x;
  s[threadIdx.x] = (i < N_NODES) ? deg[i] : 0;
  __syncthreads();
  for (int st = SCAN_CHUNK / 2; st > 0; st >>= 1) {
    if (threadIdx.x < st) s[threadIdx.x] += s[threadIdx.x + st];
    __syncthreads();
  }
  if (threadIdx.x == 0) sums[blockIdx.x] = s[0];
}

__global__ void k_topscan(int* __restrict__ sums) {
  if (threadIdx.x == 0 && blockIdx.x == 0) {
    int run = 0;
    for (int b = 0; b < N_CHUNKS; ++b) { int t = sums[b]; sums[b] = run; run += t; }
  }
}

__global__ __launch_bounds__(SCAN_CHUNK) void k_chunkscan(const int* __restrict__ deg,
                                                          const int* __restrict__ chunkOff,
                                                          int* __restrict__ offs) {
  __shared__ int s[SCAN_CHUNK];
  int i = blockIdx.x * SCAN_CHUNK + threadIdx.x;
  int v = (i < N_NODES) ? deg[i] : 0;
  s[threadIdx.x] = v;
  __syncthreads();
  for (int st = 1; st < SCAN_CHUNK; st <<= 1) {
    int t = (threadIdx.x >= st) ? s[threadIdx.x - st] : 0;
    __syncthreads();
    s[threadIdx.x] += t;
    __syncthreads();
  }
  if (i < N_NODES) offs[i + 1] = chunkOff[blockIdx.x] + s[threadIdx.x];
  if (i == 0) offs[0] = 0;
}

__global__ __launch_bounds__(256) void k_csr_fill(const int* __restrict__ src,
                                                  const int* __restrict__ dst,
                                                  const int* __restrict__ offs,
                                                  int* __restrict__ cursor,
                                                  int* __restrict__ csr_src) {
  int e = blockIdx.x * 256 + threadIdx.x;
  if (e < N_EDGES) {
    int d = dst[e];
    int p = atomicAdd(&cursor[d], 1);
    csr_src[offs[d] + p] = src[e];
  }
}

// ---------------- emb table fp32 -> bf16 ----------------
__global__ __launch_bounds__(256) void k_emb2bf(const float* __restrict__ emb,
                                                unsigned short* __restrict__ emb_b) {
  const int total = N_TOKENS * EMB_DIM / 4;
  for (int i = blockIdx.x * 256 + threadIdx.x; i < total; i += gridDim.x * 256) {
    float4 v = ((const float4*)emb)[i];
    ushort4 o;
    o.x = f2bf(v.x); o.y = f2bf(v.y); o.z = f2bf(v.z); o.w = f2bf(v.w);
    ((ushort4*)emb_b)[i] = o;
  }
}

// ---------------- W packs ----------------
__global__ __launch_bounds__(256) void k_packW1(const float* __restrict__ W,
                                                unsigned short* __restrict__ Wp) {
  int g = blockIdx.x * 256 + threadIdx.x; // 8192 total
  int lane = g & 63, jb = (g >> 6) & 15, kt = g >> 10;
  int col = jb * 16 + (lane & 15);
  int kbase = kt * 32 + (lane >> 4) * 8;
  unsigned short* o = Wp + (size_t)g * 8;
  #pragma unroll
  for (int e = 0; e < 8; ++e) o[e] = f2bf(W[(size_t)(kbase + e) * N_HIDDEN + col]);
}

__global__ __launch_bounds__(256) void k_packW2(const float* __restrict__ W,
                                                unsigned short* __restrict__ Wp) {
  int g = blockIdx.x * 256 + threadIdx.x; // 1536 total
  if (g >= 8 * 3 * 64) return;
  int lane = g & 63, jb = (g >> 6) % 3, kt = g / (3 * 64);
  int col = jb * 16 + (lane & 15);
  int kbase = kt * 32 + (lane >> 4) * 8;
  unsigned short* o = Wp + (size_t)g * 8;
  #pragma unroll
  for (int e = 0; e < 8; ++e)
    o[e] = (col < N_CLASSES) ? f2bf(W[(size_t)(kbase + e) * N_CLASSES + col]) : (unsigned short)0;
}

// ---------------- embedding + pooling, column-chunked (L2-resident slice) ----------------
// grid (12500, 8); block 256 = 4 waves = 4 nodes; chunk c = 16 dims = 8 uints.
// wave: 8 fl-lanes x 8 token-slots; each slot handles tokens {slot, slot+8, slot+16, slot+24}.
__global__ __launch_bounds__(256) void k_embedc(const int* __restrict__ feats,
                                                const unsigned int* __restrict__ rows, // emb_b
                                                unsigned int* __restrict__ h) {
  int tid = threadIdx.x;
  int w = tid >> 6, lane = tid & 63;
  int fl = lane & 7, slot = lane >> 3;
  int node = blockIdx.x * 4 + w;
  int c = blockIdx.y;

  float s0 = 0.f, s1 = 0.f, m0 = -INFINITY, m1 = -INFINITY;
  int cnt = 0;
  #pragma unroll
  for (int i = 0; i < 4; ++i) {
    int tok = feats[(size_t)node * SEQ_LEN + slot + 8 * i];
    cnt += (tok != 0);
    unsigned int v = tok ? rows[(size_t)tok * 64 + c * 8 + fl] : 0u;
    float f0 = bf2f((unsigned short)(v & 0xFFFF));
    float f1 = bf2f((unsigned short)(v >> 16));
    s0 += f0; s1 += f1;
    m0 = fmaxf(m0, f0); m1 = fmaxf(m1, f1);
  }
  #pragma unroll
  for (int mask = 8; mask <= 32; mask <<= 1) {
    s0 += __shfl_xor(s0, mask);
    s1 += __shfl_xor(s1, mask);
    m0 = fmaxf(m0, __shfl_xor(m0, mask));
    m1 = fmaxf(m1, __shfl_xor(m1, mask));
    cnt += __shfl_xor(cnt, mask);
  }
  if (slot == 0) {
    float inv = 1.0f / (float)max(cnt, 1);
    unsigned int* hv = h + (size_t)node * 128;
    hv[c * 8 + fl] = pack2bf(s0 * inv, s1 * inv);
    hv[64 + c * 8 + fl] = pack2bf(m0, m1);
  }
}

// ---------------- MFMA GEMM1 ----------------
__global__ __launch_bounds__(256) void k_mm1(const unsigned short* __restrict__ hb,
                                             const unsigned short* __restrict__ Wp,
                                             const float* __restrict__ norm_s,
                                             unsigned short* __restrict__ out) {
  __shared__ unsigned short sA[64 * 256];
  int tid = threadIdx.x;
  int r0 = blockIdx.x * 64;
  #pragma unroll
  for (int it = 0; it < 8; ++it) {
    int idx = it * 256 + tid;
    int r = idx >> 5, kb = idx & 31;
    uint4 v = make_uint4(0, 0, 0, 0);
    int row = r0 + r;
    if (row < N_NODES) v = *(const uint4*)(hb + (size_t)row * 256 + kb * 8);
    *(uint4*)&sA[r * 256 + ((kb ^ (r & 7)) << 3)] = v;
  }
  __syncthreads();

  int w = tid >> 6, lane = tid & 63;
  const short8* W8 = (const short8*)Wp;
  f32x4 acc[4][4];
  #pragma unroll
  for (int i = 0; i < 4; ++i)
    #pragma unroll
    for (int j = 0; j < 4; ++j) acc[i][j] = (f32x4){0.f, 0.f, 0.f, 0.f};

  #pragma unroll
  for (int kt = 0; kt < 8; ++kt) {
    short8 a[4], b[4];
    int kb = kt * 4 + (lane >> 4);
    #pragma unroll
    for (int ri = 0; ri < 4; ++ri) {
      int r = ri * 16 + (lane & 15);
      a[ri] = *(const short8*)&sA[r * 256 + ((kb ^ (r & 7)) << 3)];
    }
    #pragma unroll
    for (int jb = 0; jb < 4; ++jb) b[jb] = W8[(kt * 16 + w * 4 + jb) * 64 + lane];
    #pragma unroll
    for (int ri = 0; ri < 4; ++ri)
      #pragma unroll
      for (int jb = 0; jb < 4; ++jb)
        acc[ri][jb] = __builtin_amdgcn_mfma_f32_16x16x32_bf16(a[ri], b[jb], acc[ri][jb], 0, 0, 0);
  }

  #pragma unroll
  for (int ri = 0; ri < 4; ++ri) {
    #pragma unroll
    for (int rr = 0; rr < 4; ++rr) {
      int row = r0 + ri * 16 + (lane >> 4) * 4 + rr;
      if (row < N_NODES) {
        float ns = norm_s[row];
        #pragma unroll
        for (int jb = 0; jb < 4; ++jb) {
          int col = w * 64 + jb * 16 + (lane & 15);
          out[(size_t)row * 256 + col] = f2bf(acc[ri][jb][rr] * ns);
        }
      }
    }
  }
}

// ---------------- aggregation layer 1, column-chunked ----------------
// grid (12500, 8); block 256 = 4 waves = 4 nodes; chunk c = 32 feats = 16 uints.
// wave: 16 fl-lanes x 4 edge-slots.
__global__ __launch_bounds__(256) void k_agg1c(const unsigned int* __restrict__ rows, // msgb
                                               const int* __restrict__ offs,
                                               const int* __restrict__ csr_src,
                                               const float* __restrict__ norm_d,
                                               const float* __restrict__ b1,
                                               unsigned int* __restrict__ out) {
  int tid = threadIdx.x;
  int w = tid >> 6, lane = tid & 63;
  int fl = lane & 15, slot = lane >> 4;
  int node = blockIdx.x * 4 + w;
  int c = blockIdx.y;
  int beg = offs[node], end = offs[node + 1];

  float a0 = 0.f, a1 = 0.f;
  for (int e = beg + slot; e < end; e += 4) {
    int s = csr_src[e];
    unsigned int v = rows[(size_t)s * 128 + c * 16 + fl];
    a0 += bf2f((unsigned short)(v & 0xFFFF));
    a1 += bf2f((unsigned short)(v >> 16));
  }
  a0 += __shfl_xor(a0, 16); a1 += __shfl_xor(a1, 16);
  a0 += __shfl_xor(a0, 32); a1 += __shfl_xor(a1, 32);

  if (slot == 0) {
    float nd = norm_d[node];
    int fi = c * 32 + 2 * fl;
    float o0 = fmaxf(a0 * nd + b1[fi], 0.f);
    float o1 = fmaxf(a1 * nd + b1[fi + 1], 0.f);
    out[(size_t)node * 128 + c * 16 + fl] = pack2bf(o0, o1);
  }
}

// ---------------- MFMA GEMM2 ----------------
__global__ __launch_bounds__(256) void k_mm2(const unsigned short* __restrict__ h2b,
                                             const unsigned short* __restrict__ Wp,
                                             const float* __restrict__ norm_s,
                                             unsigned short* __restrict__ out) {
  __shared__ unsigned short sA[64 * 256];
  int tid = threadIdx.x;
  int r0 = blockIdx.x * 64;
  #pragma unroll
  for (int it = 0; it < 8; ++it) {
    int idx = it * 256 + tid;
    int r = idx >> 5, kb = idx & 31;
    uint4 v = make_uint4(0, 0, 0, 0);
    int row = r0 + r;
    if (row < N_NODES) v = *(const uint4*)(h2b + (size_t)row * 256 + kb * 8);
    *(uint4*)&sA[r * 256 + ((kb ^ (r & 7)) << 3)] = v;
  }
  __syncthreads();

  int w = tid >> 6, lane = tid & 63;
  const short8* W8 = (const short8*)Wp;
  f32x4 acc[3];
  #pragma unroll
  for (int j = 0; j < 3; ++j) acc[j] = (f32x4){0.f, 0.f, 0.f, 0.f};

  #pragma unroll
  for (int kt = 0; kt < 8; ++kt) {
    int r = w * 16 + (lane & 15);
    int kb = kt * 4 + (lane >> 4);
    short8 a = *(const short8*)&sA[r * 256 + ((kb ^ (r & 7)) << 3)];
    #pragma unroll
    for (int jb = 0; jb < 3; ++jb) {
      short8 b = W8[(kt * 3 + jb) * 64 + lane];
      acc[jb] = __builtin_amdgcn_mfma_f32_16x16x32_bf16(a, b, acc[jb], 0, 0, 0);
    }
  }

  #pragma unroll
  for (int rr = 0; rr < 4; ++rr) {
    int row = r0 + w * 16 + (lane >> 4) * 4 + rr;
    if (row < N_NODES) {
      float ns = norm_s[row];
      #pragma unroll
      for (int jb = 0; jb < 3; ++jb) {
        int col = jb * 16 + (lane & 15);
        if (col < N_CLASSES) out[(size_t)row * N_CLASSES + col] = f2bf(acc[jb][rr] * ns);
      }
    }
  }
}

// ---------------- aggregation layer 2 (uint loads, 3 edge-slots x 20 lanes) ----------------
__global__ __launch_bounds__(256) void k_agg2(const unsigned int* __restrict__ rows, // hw2b
                                              const int* __restrict__ offs,
                                              const int* __restrict__ csr_src,
                                              const float* __restrict__ norm_d,
                                              const float* __restrict__ b2,
                                              float* __restrict__ out) {
  int tid = threadIdx.x;
  int w = tid >> 6, lane = tid & 63;
  int node = blockIdx.x * 4 + w;
  int slot = lane / 20, fl = lane % 20; // slot 3 idle
  int beg = offs[node], end = offs[node + 1];

  float a0 = 0.f, a1 = 0.f;
  if (slot < 3) {
    for (int e = beg + slot; e < end; e += 3) {
      int s = csr_src[e];
      unsigned int v = rows[(size_t)s * 20 + fl];
      a0 += bf2f((unsigned short)(v & 0xFFFF));
      a1 += bf2f((unsigned short)(v >> 16));
    }
  }
  float p0 = __shfl(a0, lane + 20), p1 = __shfl(a1, lane + 20);
  float q0 = __shfl(a0, lane + 40), q1 = __shfl(a1, lane + 40);
  if (slot == 0) {
    a0 += p0 + q0; a1 += p1 + q1;
    float nd = norm_d[node];
    float o0 = a0 * nd + b2[2 * fl];
    float o1 = a1 * nd + b2[2 * fl + 1];
    *(float2*)&out[(size_t)node * N_CLASSES + 2 * fl] = make_float2(o0, o1);
  }
}

extern "C" void kernel_launch(void* const* d_in, const int* in_sizes, int n_in,
                              void* d_out, int out_size, void* d_ws, size_t ws_size,
                              hipStream_t stream) {
  const int*   feats = (const int*)d_in[0];
  const int*   src   = (const int*)d_in[1];
  const int*   dst   = (const int*)d_in[2];
  const float* emb   = (const float*)d_in[3];
  const float* W1    = (const float*)d_in[4];
  const float* b1    = (const float*)d_in[5];
  const float* W2    = (const float*)d_in[6];
  const float* b2    = (const float*)d_in[7];
  float* out = (float*)d_out;

  char* base = (char*)d_ws;
  size_t off = 0;
  auto alloc = [&](size_t bytes) -> char* {
    char* p = base + off;
    off += (bytes + 255) & ~(size_t)255;
    return p;
  };
  unsigned short* hb      = (unsigned short*)alloc((size_t)N_NODES * IN_FEATS * 2);  // h bf16; reused as h2b
  unsigned short* msgb    = (unsigned short*)alloc((size_t)N_NODES * N_HIDDEN * 2);
  unsigned short* hw2b    = (unsigned short*)alloc((size_t)N_NODES * N_CLASSES * 2);
  unsigned short* emb_b   = (unsigned short*)alloc((size_t)N_TOKENS * EMB_DIM * 2);
  unsigned short* Wp1     = (unsigned short*)alloc((size_t)8 * 16 * 64 * 8 * 2);
  unsigned short* Wp2     = (unsigned short*)alloc((size_t)8 * 3 * 64 * 8 * 2);
  int*   deg_out = (int*)alloc((size_t)3 * N_NODES * 4);
  int*   deg_in  = deg_out + N_NODES;
  int*   cursor  = deg_in + N_NODES;
  float* norm_s  = (float*)alloc((size_t)N_NODES * 4);
  float* norm_d  = (float*)alloc((size_t)N_NODES * 4);
  int*   offs    = (int*)alloc((size_t)(N_NODES + 1) * 4);
  int*   csums   = (int*)alloc((size_t)N_CHUNKS * 4);
  int*   csr_src = (int*)alloc((size_t)N_EDGES * 4);

  hipMemsetAsync(deg_out, 0, (size_t)3 * N_NODES * 4, stream);

  int eb = (N_EDGES + 255) / 256;
  int nb = (N_NODES + 255) / 256;
  k_emb2bf<<<2048, 256, 0, stream>>>(emb, emb_b);
  k_packW1<<<32, 256, 0, stream>>>(W1, Wp1);
  k_packW2<<<6, 256, 0, stream>>>(W2, Wp2);
  k_degree<<<eb, 256, 0, stream>>>(src, dst, deg_out, deg_in);
  k_norm<<<nb, 256, 0, stream>>>(deg_out, deg_in, norm_s, norm_d);
  k_chunksum<<<N_CHUNKS, SCAN_CHUNK, 0, stream>>>(deg_in, csums);
  k_topscan<<<1, 64, 0, stream>>>(csums);
  k_chunkscan<<<N_CHUNKS, SCAN_CHUNK, 0, stream>>>(deg_in, csums, offs);
  k_csr_fill<<<eb, 256, 0, stream>>>(src, dst, offs, cursor, csr_src);

  int gemm_blocks = (N_NODES + 63) / 64; // 782
  k_embedc<<<dim3(N_NODES / 4, 8), 256, 0, stream>>>(feats, (const unsigned int*)emb_b, (unsigned int*)hb);
  k_mm1<<<gemm_blocks, 256, 0, stream>>>(hb, Wp1, norm_s, msgb);
  k_agg1c<<<dim3(N_NODES / 4, 8), 256, 0, stream>>>((const unsigned int*)msgb, offs, csr_src, norm_d, b1, (unsigned int*)hb);
  k_mm2<<<gemm_blocks, 256, 0, stream>>>(hb, Wp2, norm_s, hw2b);
  k_agg2<<<N_NODES / 4, 256, 0, stream>>>((const unsigned int*)hw2b, offs, csr_src, norm_d, b2, out);
}

// Round 5
// 534.629 us; speedup vs baseline: 1.0642x; 1.0642x over previous
//
#include <hip/hip_runtime.h>
#include <math.h>

#define N_NODES 50000
#define SEQ_LEN 32
#define EMB_DIM 128
#define IN_FEATS 256
#define N_HIDDEN 256
#define N_CLASSES 40
#define N_EDGES 800000
#define N_TOKENS 100000

constexpr int SCAN_CHUNK = 512;
constexpr int N_CHUNKS = (N_NODES + SCAN_CHUNK - 1) / SCAN_CHUNK; // 98

typedef short short8 __attribute__((ext_vector_type(8)));
typedef float f32x4 __attribute__((ext_vector_type(4)));

__device__ __forceinline__ unsigned short f2bf(float x) {
  unsigned int u = __float_as_uint(x);
  unsigned int r = (u + 0x7FFFu + ((u >> 16) & 1u)) >> 16; // RTNE
  return (unsigned short)r;
}
__device__ __forceinline__ float bf2f(unsigned short s) {
  return __uint_as_float((unsigned int)s << 16);
}
__device__ __forceinline__ unsigned int pack2bf(float a, float b) {
  return (unsigned int)f2bf(a) | ((unsigned int)f2bf(b) << 16);
}

// ---------------- degree / norms ----------------
__global__ __launch_bounds__(256) void k_degree(const int* __restrict__ src,
                                                const int* __restrict__ dst,
                                                int* __restrict__ deg_out,
                                                int* __restrict__ deg_in) {
  int e = blockIdx.x * 256 + threadIdx.x;
  if (e < N_EDGES) {
    atomicAdd(&deg_out[src[e]], 1);
    atomicAdd(&deg_in[dst[e]], 1);
  }
}

__global__ __launch_bounds__(256) void k_norm(const int* __restrict__ deg_out,
                                              const int* __restrict__ deg_in,
                                              float* __restrict__ norm_s,
                                              float* __restrict__ norm_d) {
  int i = blockIdx.x * 256 + threadIdx.x;
  if (i < N_NODES) {
    norm_s[i] = 1.0f / sqrtf((float)max(deg_out[i], 1));
    norm_d[i] = 1.0f / sqrtf((float)max(deg_in[i], 1));
  }
}

// ---------------- seq_inv: 1/count(nonzero tokens) per node ----------------
// block 256 = 4 waves; wave = 2 nodes x 32 lanes.
__global__ __launch_bounds__(256) void k_seqinv(const int* __restrict__ feats,
                                                float* __restrict__ inv) {
  int tid = threadIdx.x;
  int node = blockIdx.x * 8 + (tid >> 5);
  int l32 = tid & 31;
  int tok = feats[(size_t)node * SEQ_LEN + l32];
  unsigned long long m = __ballot(tok != 0);
  int half = (tid >> 5) & 1;
  int cnt = half ? (int)__popcll(m >> 32) : (int)__popcll(m & 0xFFFFFFFFull);
  if (l32 == 0) inv[node] = 1.0f / (float)max(cnt, 1);
}

// ---------------- scan ----------------
__global__ __launch_bounds__(SCAN_CHUNK) void k_chunksum(const int* __restrict__ deg,
                                                         int* __restrict__ sums) {
  __shared__ int s[SCAN_CHUNK];
  int i = blockIdx.x * SCAN_CHUNK + threadIdx.x;
  s[threadIdx.x] = (i < N_NODES) ? deg[i] : 0;
  __syncthreads();
  for (int st = SCAN_CHUNK / 2; st > 0; st >>= 1) {
    if (threadIdx.x < st) s[threadIdx.x] += s[threadIdx.x + st];
    __syncthreads();
  }
  if (threadIdx.x == 0) sums[blockIdx.x] = s[0];
}

__global__ void k_topscan(int* __restrict__ sums) {
  if (threadIdx.x == 0 && blockIdx.x == 0) {
    int run = 0;
    for (int b = 0; b < N_CHUNKS; ++b) { int t = sums[b]; sums[b] = run; run += t; }
  }
}

__global__ __launch_bounds__(SCAN_CHUNK) void k_chunkscan(const int* __restrict__ deg,
                                                          const int* __restrict__ chunkOff,
                                                          int* __restrict__ offs) {
  __shared__ int s[SCAN_CHUNK];
  int i = blockIdx.x * SCAN_CHUNK + threadIdx.x;
  int v = (i < N_NODES) ? deg[i] : 0;
  s[threadIdx.x] = v;
  __syncthreads();
  for (int st = 1; st < SCAN_CHUNK; st <<= 1) {
    int t = (threadIdx.x >= st) ? s[threadIdx.x - st] : 0;
    __syncthreads();
    s[threadIdx.x] += t;
    __syncthreads();
  }
  if (i < N_NODES) offs[i + 1] = chunkOff[blockIdx.x] + s[threadIdx.x];
  if (i == 0) offs[0] = 0;
}

__global__ __launch_bounds__(256) void k_csr_fill(const int* __restrict__ src,
                                                  const int* __restrict__ dst,
                                                  const int* __restrict__ offs,
                                                  int* __restrict__ cursor,
                                                  int* __restrict__ csr_src) {
  int e = blockIdx.x * 256 + threadIdx.x;
  if (e < N_EDGES) {
    int d = dst[e];
    int p = atomicAdd(&cursor[d], 1);
    csr_src[offs[d] + p] = src[e];
  }
}

// ---------------- emb table fp32 -> bf16 ----------------
__global__ __launch_bounds__(256) void k_emb2bf(const float* __restrict__ emb,
                                                unsigned short* __restrict__ emb_b) {
  const int total = N_TOKENS * EMB_DIM / 4;
  for (int i = blockIdx.x * 256 + threadIdx.x; i < total; i += gridDim.x * 256) {
    float4 v = ((const float4*)emb)[i];
    ushort4 o;
    o.x = f2bf(v.x); o.y = f2bf(v.y); o.z = f2bf(v.z); o.w = f2bf(v.w);
    ((ushort4*)emb_b)[i] = o;
  }
}

// ---------------- W packs ----------------
__global__ __launch_bounds__(256) void k_packW1(const float* __restrict__ W,
                                                unsigned short* __restrict__ Wp) {
  int g = blockIdx.x * 256 + threadIdx.x; // 8192 total
  int lane = g & 63, jb = (g >> 6) & 15, kt = g >> 10;
  int col = jb * 16 + (lane & 15);
  int kbase = kt * 32 + (lane >> 4) * 8;
  unsigned short* o = Wp + (size_t)g * 8;
  #pragma unroll
  for (int e = 0; e < 8; ++e) o[e] = f2bf(W[(size_t)(kbase + e) * N_HIDDEN + col]);
}

__global__ __launch_bounds__(256) void k_packW2(const float* __restrict__ W,
                                                unsigned short* __restrict__ Wp) {
  int g = blockIdx.x * 256 + threadIdx.x; // 1536 total
  if (g >= 8 * 3 * 64) return;
  int lane = g & 63, jb = (g >> 6) % 3, kt = g / (3 * 64);
  int col = jb * 16 + (lane & 15);
  int kbase = kt * 32 + (lane >> 4) * 8;
  unsigned short* o = Wp + (size_t)g * 8;
  #pragma unroll
  for (int e = 0; e < 8; ++e)
    o[e] = (col < N_CLASSES) ? f2bf(W[(size_t)(kbase + e) * N_CLASSES + col]) : (unsigned short)0;
}

// ---------------- embedding + pooling, XCD-PINNED column chunks ----------------
// grid 12500*8; c = blockIdx.x & 7 -> pinned to XCD c (round-robin dispatch).
// block 256 = 4 waves = 4 nodes; chunk c = 16 dims = 8 uints (slice 3.2MB/XCD).
// wave: 8 fl-lanes x 8 token-slots; slot handles tokens {slot, slot+8, +16, +24}.
__global__ __launch_bounds__(256) void k_embedc(const int* __restrict__ feats,
                                                const unsigned int* __restrict__ rows, // emb_b
                                                const float* __restrict__ inv_seq,
                                                unsigned int* __restrict__ h) {
  int tid = threadIdx.x;
  int w = tid >> 6, lane = tid & 63;
  int fl = lane & 7, slot = lane >> 3;
  int c = blockIdx.x & 7;
  int node = (blockIdx.x >> 3) * 4 + w;

  float s0 = 0.f, s1 = 0.f, m0 = -INFINITY, m1 = -INFINITY;
  #pragma unroll
  for (int i = 0; i < 4; ++i) {
    int tok = feats[(size_t)node * SEQ_LEN + slot + 8 * i];
    unsigned int v = tok ? rows[(size_t)tok * 64 + c * 8 + fl] : 0u;
    float f0 = bf2f((unsigned short)(v & 0xFFFF));
    float f1 = bf2f((unsigned short)(v >> 16));
    s0 += f0; s1 += f1;
    m0 = fmaxf(m0, f0); m1 = fmaxf(m1, f1);
  }
  #pragma unroll
  for (int mask = 8; mask <= 32; mask <<= 1) {
    s0 += __shfl_xor(s0, mask);
    s1 += __shfl_xor(s1, mask);
    m0 = fmaxf(m0, __shfl_xor(m0, mask));
    m1 = fmaxf(m1, __shfl_xor(m1, mask));
  }
  if (slot == 0) {
    float inv = inv_seq[node];
    unsigned int* hv = h + (size_t)node * 128;
    hv[c * 8 + fl] = pack2bf(s0 * inv, s1 * inv);
    hv[64 + c * 8 + fl] = pack2bf(m0, m1);
  }
}

// ---------------- MFMA GEMM1 ----------------
__global__ __launch_bounds__(256) void k_mm1(const unsigned short* __restrict__ hb,
                                             const unsigned short* __restrict__ Wp,
                                             const float* __restrict__ norm_s,
                                             unsigned short* __restrict__ out) {
  __shared__ unsigned short sA[64 * 256];
  int tid = threadIdx.x;
  int r0 = blockIdx.x * 64;
  #pragma unroll
  for (int it = 0; it < 8; ++it) {
    int idx = it * 256 + tid;
    int r = idx >> 5, kb = idx & 31;
    uint4 v = make_uint4(0, 0, 0, 0);
    int row = r0 + r;
    if (row < N_NODES) v = *(const uint4*)(hb + (size_t)row * 256 + kb * 8);
    *(uint4*)&sA[r * 256 + ((kb ^ (r & 7)) << 3)] = v;
  }
  __syncthreads();

  int w = tid >> 6, lane = tid & 63;
  const short8* W8 = (const short8*)Wp;
  f32x4 acc[4][4];
  #pragma unroll
  for (int i = 0; i < 4; ++i)
    #pragma unroll
    for (int j = 0; j < 4; ++j) acc[i][j] = (f32x4){0.f, 0.f, 0.f, 0.f};

  #pragma unroll
  for (int kt = 0; kt < 8; ++kt) {
    short8 a[4], b[4];
    int kb = kt * 4 + (lane >> 4);
    #pragma unroll
    for (int ri = 0; ri < 4; ++ri) {
      int r = ri * 16 + (lane & 15);
      a[ri] = *(const short8*)&sA[r * 256 + ((kb ^ (r & 7)) << 3)];
    }
    #pragma unroll
    for (int jb = 0; jb < 4; ++jb) b[jb] = W8[(kt * 16 + w * 4 + jb) * 64 + lane];
    #pragma unroll
    for (int ri = 0; ri < 4; ++ri)
      #pragma unroll
      for (int jb = 0; jb < 4; ++jb)
        acc[ri][jb] = __builtin_amdgcn_mfma_f32_16x16x32_bf16(a[ri], b[jb], acc[ri][jb], 0, 0, 0);
  }

  #pragma unroll
  for (int ri = 0; ri < 4; ++ri) {
    #pragma unroll
    for (int rr = 0; rr < 4; ++rr) {
      int row = r0 + ri * 16 + (lane >> 4) * 4 + rr;
      if (row < N_NODES) {
        float ns = norm_s[row];
        #pragma unroll
        for (int jb = 0; jb < 4; ++jb) {
          int col = w * 64 + jb * 16 + (lane & 15);
          out[(size_t)row * 256 + col] = f2bf(acc[ri][jb][rr] * ns);
        }
      }
    }
  }
}

// ---------------- aggregation layer 1, XCD-PINNED column chunks ----------------
// grid 12500*8; c = blockIdx.x & 7 (pinned slice, 3.2MB/XCD L2-resident).
// block 256 = 4 waves = 4 nodes; wave: 16 fl-lanes x 4 edge-slots, 2x unroll.
__global__ __launch_bounds__(256) void k_agg1c(const unsigned int* __restrict__ rows, // msgb
                                               const int* __restrict__ offs,
                                               const int* __restrict__ csr_src,
                                               const float* __restrict__ norm_d,
                                               const float* __restrict__ b1,
                                               unsigned int* __restrict__ out) {
  int tid = threadIdx.x;
  int w = tid >> 6, lane = tid & 63;
  int fl = lane & 15, slot = lane >> 4;
  int c = blockIdx.x & 7;
  int node = (blockIdx.x >> 3) * 4 + w;
  int beg = offs[node], end = offs[node + 1];

  float a0 = 0.f, a1 = 0.f;
  int e = beg + slot;
  for (; e + 4 < end; e += 8) {
    int sa = csr_src[e], sb = csr_src[e + 4];
    unsigned int va = rows[(size_t)sa * 128 + c * 16 + fl];
    unsigned int vb = rows[(size_t)sb * 128 + c * 16 + fl];
    a0 += bf2f((unsigned short)(va & 0xFFFF)); a1 += bf2f((unsigned short)(va >> 16));
    a0 += bf2f((unsigned short)(vb & 0xFFFF)); a1 += bf2f((unsigned short)(vb >> 16));
  }
  if (e < end) {
    unsigned int v = rows[(size_t)csr_src[e] * 128 + c * 16 + fl];
    a0 += bf2f((unsigned short)(v & 0xFFFF));
    a1 += bf2f((unsigned short)(v >> 16));
  }
  a0 += __shfl_xor(a0, 16); a1 += __shfl_xor(a1, 16);
  a0 += __shfl_xor(a0, 32); a1 += __shfl_xor(a1, 32);

  if (slot == 0) {
    float nd = norm_d[node];
    int fi = c * 32 + 2 * fl;
    float o0 = fmaxf(a0 * nd + b1[fi], 0.f);
    float o1 = fmaxf(a1 * nd + b1[fi + 1], 0.f);
    out[(size_t)node * 128 + c * 16 + fl] = pack2bf(o0, o1);
  }
}

// ---------------- MFMA GEMM2 ----------------
__global__ __launch_bounds__(256) void k_mm2(const unsigned short* __restrict__ h2b,
                                             const unsigned short* __restrict__ Wp,
                                             const float* __restrict__ norm_s,
                                             unsigned short* __restrict__ out) {
  __shared__ unsigned short sA[64 * 256];
  int tid = threadIdx.x;
  int r0 = blockIdx.x * 64;
  #pragma unroll
  for (int it = 0; it < 8; ++it) {
    int idx = it * 256 + tid;
    int r = idx >> 5, kb = idx & 31;
    uint4 v = make_uint4(0, 0, 0, 0);
    int row = r0 + r;
    if (row < N_NODES) v = *(const uint4*)(h2b + (size_t)row * 256 + kb * 8);
    *(uint4*)&sA[r * 256 + ((kb ^ (r & 7)) << 3)] = v;
  }
  __syncthreads();

  int w = tid >> 6, lane = tid & 63;
  const short8* W8 = (const short8*)Wp;
  f32x4 acc[3];
  #pragma unroll
  for (int j = 0; j < 3; ++j) acc[j] = (f32x4){0.f, 0.f, 0.f, 0.f};

  #pragma unroll
  for (int kt = 0; kt < 8; ++kt) {
    int r = w * 16 + (lane & 15);
    int kb = kt * 4 + (lane >> 4);
    short8 a = *(const short8*)&sA[r * 256 + ((kb ^ (r & 7)) << 3)];
    #pragma unroll
    for (int jb = 0; jb < 3; ++jb) {
      short8 b = W8[(kt * 3 + jb) * 64 + lane];
      acc[jb] = __builtin_amdgcn_mfma_f32_16x16x32_bf16(a, b, acc[jb], 0, 0, 0);
    }
  }

  #pragma unroll
  for (int rr = 0; rr < 4; ++rr) {
    int row = r0 + w * 16 + (lane >> 4) * 4 + rr;
    if (row < N_NODES) {
      float ns = norm_s[row];
      #pragma unroll
      for (int jb = 0; jb < 3; ++jb) {
        int col = jb * 16 + (lane & 15);
        if (col < N_CLASSES) out[(size_t)row * N_CLASSES + col] = f2bf(acc[jb][rr] * ns);
      }
    }
  }
}

// ---------------- aggregation layer 2 (uint loads, 3 edge-slots x 20 lanes) ----------------
__global__ __launch_bounds__(256) void k_agg2(const unsigned int* __restrict__ rows, // hw2b
                                              const int* __restrict__ offs,
                                              const int* __restrict__ csr_src,
                                              const float* __restrict__ norm_d,
                                              const float* __restrict__ b2,
                                              float* __restrict__ out) {
  int tid = threadIdx.x;
  int w = tid >> 6, lane = tid & 63;
  int node = blockIdx.x * 4 + w;
  int slot = lane / 20, fl = lane % 20; // slot 3 idle
  int beg = offs[node], end = offs[node + 1];

  float a0 = 0.f, a1 = 0.f;
  if (slot < 3) {
    for (int e = beg + slot; e < end; e += 3) {
      int s = csr_src[e];
      unsigned int v = rows[(size_t)s * 20 + fl];
      a0 += bf2f((unsigned short)(v & 0xFFFF));
      a1 += bf2f((unsigned short)(v >> 16));
    }
  }
  float p0 = __shfl(a0, lane + 20), p1 = __shfl(a1, lane + 20);
  float q0 = __shfl(a0, lane + 40), q1 = __shfl(a1, lane + 40);
  if (slot == 0) {
    a0 += p0 + q0; a1 += p1 + q1;
    float nd = norm_d[node];
    float o0 = a0 * nd + b2[2 * fl];
    float o1 = a1 * nd + b2[2 * fl + 1];
    *(float2*)&out[(size_t)node * N_CLASSES + 2 * fl] = make_float2(o0, o1);
  }
}

extern "C" void kernel_launch(void* const* d_in, const int* in_sizes, int n_in,
                              void* d_out, int out_size, void* d_ws, size_t ws_size,
                              hipStream_t stream) {
  const int*   feats = (const int*)d_in[0];
  const int*   src   = (const int*)d_in[1];
  const int*   dst   = (const int*)d_in[2];
  const float* emb   = (const float*)d_in[3];
  const float* W1    = (const float*)d_in[4];
  const float* b1    = (const float*)d_in[5];
  const float* W2    = (const float*)d_in[6];
  const float* b2    = (const float*)d_in[7];
  float* out = (float*)d_out;

  char* base = (char*)d_ws;
  size_t off = 0;
  auto alloc = [&](size_t bytes) -> char* {
    char* p = base + off;
    off += (bytes + 255) & ~(size_t)255;
    return p;
  };
  unsigned short* hb      = (unsigned short*)alloc((size_t)N_NODES * IN_FEATS * 2);  // h bf16; reused as h2b
  unsigned short* msgb    = (unsigned short*)alloc((size_t)N_NODES * N_HIDDEN * 2);
  unsigned short* hw2b    = (unsigned short*)alloc((size_t)N_NODES * N_CLASSES * 2);
  unsigned short* emb_b   = (unsigned short*)alloc((size_t)N_TOKENS * EMB_DIM * 2);
  unsigned short* Wp1     = (unsigned short*)alloc((size_t)8 * 16 * 64 * 8 * 2);
  unsigned short* Wp2     = (unsigned short*)alloc((size_t)8 * 3 * 64 * 8 * 2);
  int*   deg_out = (int*)alloc((size_t)3 * N_NODES * 4);
  int*   deg_in  = deg_out + N_NODES;
  int*   cursor  = deg_in + N_NODES;
  float* norm_s  = (float*)alloc((size_t)N_NODES * 4);
  float* norm_d  = (float*)alloc((size_t)N_NODES * 4);
  float* inv_seq = (float*)alloc((size_t)N_NODES * 4);
  int*   offs    = (int*)alloc((size_t)(N_NODES + 1) * 4);
  int*   csums   = (int*)alloc((size_t)N_CHUNKS * 4);
  int*   csr_src = (int*)alloc((size_t)N_EDGES * 4);

  hipMemsetAsync(deg_out, 0, (size_t)3 * N_NODES * 4, stream);

  int eb = (N_EDGES + 255) / 256;
  int nb = (N_NODES + 255) / 256;
  k_emb2bf<<<2048, 256, 0, stream>>>(emb, emb_b);
  k_packW1<<<32, 256, 0, stream>>>(W1, Wp1);
  k_packW2<<<6, 256, 0, stream>>>(W2, Wp2);
  k_seqinv<<<N_NODES / 8, 256, 0, stream>>>(feats, inv_seq);
  k_degree<<<eb, 256, 0, stream>>>(src, dst, deg_out, deg_in);
  k_norm<<<nb, 256, 0, stream>>>(deg_out, deg_in, norm_s, norm_d);
  k_chunksum<<<N_CHUNKS, SCAN_CHUNK, 0, stream>>>(deg_in, csums);
  k_topscan<<<1, 64, 0, stream>>>(csums);
  k_chunkscan<<<N_CHUNKS, SCAN_CHUNK, 0, stream>>>(deg_in, csums, offs);
  k_csr_fill<<<eb, 256, 0, stream>>>(src, dst, offs, cursor, csr_src);

  int gemm_blocks = (N_NODES + 63) / 64; // 782
  k_embedc<<<(N_NODES / 4) * 8, 256, 0, stream>>>(feats, (const unsigned int*)emb_b, inv_seq, (unsigned int*)hb);
  k_mm1<<<gemm_blocks, 256, 0, stream>>>(hb, Wp1, norm_s, msgb);
  k_agg1c<<<(N_NODES / 4) * 8, 256, 0, stream>>>((const unsigned int*)msgb, offs, csr_src, norm_d, b1, (unsigned int*)hb);
  k_mm2<<<gemm_blocks, 256, 0, stream>>>(hb, Wp2, norm_s, hw2b);
  k_agg2<<<N_NODES / 4, 256, 0, stream>>>((const unsigned int*)hw2b, offs, csr_src, norm_d, b2, out);
}

// Round 6
// 307.720 us; speedup vs baseline: 1.8489x; 1.7374x over previous
//
#include <hip/hip_runtime.h>
#include <math.h>

#define N_NODES 50000
#define SEQ_LEN 32
#define EMB_DIM 128
#define IN_FEATS 256
#define N_HIDDEN 256
#define N_CLASSES 40
#define N_EDGES 800000
#define N_TOKENS 100000

constexpr int SCAN_CHUNK = 512;
constexpr int N_CHUNKS = (N_NODES + SCAN_CHUNK - 1) / SCAN_CHUNK; // 98

typedef short short8 __attribute__((ext_vector_type(8)));
typedef float f32x4 __attribute__((ext_vector_type(4)));

__device__ __forceinline__ unsigned short f2bf(float x) {
  unsigned int u = __float_as_uint(x);
  unsigned int r = (u + 0x7FFFu + ((u >> 16) & 1u)) >> 16; // RTNE
  return (unsigned short)r;
}
__device__ __forceinline__ float bf2f(unsigned short s) {
  return __uint_as_float((unsigned int)s << 16);
}
__device__ __forceinline__ unsigned int pack2bf(float a, float b) {
  return (unsigned int)f2bf(a) | ((unsigned int)f2bf(b) << 16);
}

// ---------------- degree / norms ----------------
__global__ __launch_bounds__(256) void k_degree(const int* __restrict__ src,
                                                const int* __restrict__ dst,
                                                int* __restrict__ deg_out,
                                                int* __restrict__ deg_in) {
  int e = blockIdx.x * 256 + threadIdx.x;
  if (e < N_EDGES) {
    atomicAdd(&deg_out[src[e]], 1);
    atomicAdd(&deg_in[dst[e]], 1);
  }
}

__global__ __launch_bounds__(256) void k_norm(const int* __restrict__ deg_out,
                                              const int* __restrict__ deg_in,
                                              float* __restrict__ norm_s,
                                              float* __restrict__ norm_d) {
  int i = blockIdx.x * 256 + threadIdx.x;
  if (i < N_NODES) {
    norm_s[i] = 1.0f / sqrtf((float)max(deg_out[i], 1));
    norm_d[i] = 1.0f / sqrtf((float)max(deg_in[i], 1));
  }
}

// ---------------- scan ----------------
__global__ __launch_bounds__(SCAN_CHUNK) void k_chunksum(const int* __restrict__ deg,
                                                         int* __restrict__ sums) {
  __shared__ int s[SCAN_CHUNK];
  int i = blockIdx.x * SCAN_CHUNK + threadIdx.x;
  s[threadIdx.x] = (i < N_NODES) ? deg[i] : 0;
  __syncthreads();
  for (int st = SCAN_CHUNK / 2; st > 0; st >>= 1) {
    if (threadIdx.x < st) s[threadIdx.x] += s[threadIdx.x + st];
    __syncthreads();
  }
  if (threadIdx.x == 0) sums[blockIdx.x] = s[0];
}

__global__ void k_topscan(int* __restrict__ sums) {
  if (threadIdx.x == 0 && blockIdx.x == 0) {
    int run = 0;
    for (int b = 0; b < N_CHUNKS; ++b) { int t = sums[b]; sums[b] = run; run += t; }
  }
}

__global__ __launch_bounds__(SCAN_CHUNK) void k_chunkscan(const int* __restrict__ deg,
                                                          const int* __restrict__ chunkOff,
                                                          int* __restrict__ offs) {
  __shared__ int s[SCAN_CHUNK];
  int i = blockIdx.x * SCAN_CHUNK + threadIdx.x;
  int v = (i < N_NODES) ? deg[i] : 0;
  s[threadIdx.x] = v;
  __syncthreads();
  for (int st = 1; st < SCAN_CHUNK; st <<= 1) {
    int t = (threadIdx.x >= st) ? s[threadIdx.x - st] : 0;
    __syncthreads();
    s[threadIdx.x] += t;
    __syncthreads();
  }
  if (i < N_NODES) offs[i + 1] = chunkOff[blockIdx.x] + s[threadIdx.x];
  if (i == 0) offs[0] = 0;
}

__global__ __launch_bounds__(256) void k_csr_fill(const int* __restrict__ src,
                                                  const int* __restrict__ dst,
                                                  const int* __restrict__ offs,
                                                  int* __restrict__ cursor,
                                                  int* __restrict__ csr_src) {
  int e = blockIdx.x * 256 + threadIdx.x;
  if (e < N_EDGES) {
    int d = dst[e];
    int p = atomicAdd(&cursor[d], 1);
    csr_src[offs[d] + p] = src[e];
  }
}

// ---------------- emb table fp32 -> bf16 ----------------
__global__ __launch_bounds__(256) void k_emb2bf(const float* __restrict__ emb,
                                                unsigned short* __restrict__ emb_b) {
  const int total = N_TOKENS * EMB_DIM / 4;
  for (int i = blockIdx.x * 256 + threadIdx.x; i < total; i += gridDim.x * 256) {
    float4 v = ((const float4*)emb)[i];
    ushort4 o;
    o.x = f2bf(v.x); o.y = f2bf(v.y); o.z = f2bf(v.z); o.w = f2bf(v.w);
    ((ushort4*)emb_b)[i] = o;
  }
}

// ---------------- W packs ----------------
__global__ __launch_bounds__(256) void k_packW1(const float* __restrict__ W,
                                                unsigned short* __restrict__ Wp) {
  int g = blockIdx.x * 256 + threadIdx.x; // 8192 total
  int lane = g & 63, jb = (g >> 6) & 15, kt = g >> 10;
  int col = jb * 16 + (lane & 15);
  int kbase = kt * 32 + (lane >> 4) * 8;
  unsigned short* o = Wp + (size_t)g * 8;
  #pragma unroll
  for (int e = 0; e < 8; ++e) o[e] = f2bf(W[(size_t)(kbase + e) * N_HIDDEN + col]);
}

__global__ __launch_bounds__(256) void k_packW2(const float* __restrict__ W,
                                                unsigned short* __restrict__ Wp) {
  int g = blockIdx.x * 256 + threadIdx.x; // 1536 total
  if (g >= 8 * 3 * 64) return;
  int lane = g & 63, jb = (g >> 6) % 3, kt = g / (3 * 64);
  int col = jb * 16 + (lane & 15);
  int kbase = kt * 32 + (lane >> 4) * 8;
  unsigned short* o = Wp + (size_t)g * 8;
  #pragma unroll
  for (int e = 0; e < 8; ++e)
    o[e] = (col < N_CLASSES) ? f2bf(W[(size_t)(kbase + e) * N_CLASSES + col]) : (unsigned short)0;
}

// ---------------- embedding + pooling: 1 wave = 1 node, uint2/lane ----------------
// 32-lane halves each load one token row slice (laneL covers dims 4*laneL..4*laneL+3).
// Two tokens in flight per iteration; 16 iterations fully unrolled.
__global__ __launch_bounds__(256) void k_embed(const int* __restrict__ feats,
                                               const uint2* __restrict__ rows2, // emb_b as uint2 (32/row)
                                               uint2* __restrict__ h) {        // h as uint2 (64/row)
  int tid = threadIdx.x;
  int w = tid >> 6, lane = tid & 63;
  int node = blockIdx.x * 4 + w;
  int laneL = lane & 31, half = lane >> 5;

  int tok0 = feats[(size_t)node * SEQ_LEN + laneL]; // both halves read same (broadcast)
  unsigned long long m = __ballot(laneL < 32 && tok0 != 0);
  int cnt = (int)__popcll(m & 0xFFFFFFFFull);
  float inv = 1.0f / (float)max(cnt, 1);

  float s0 = 0.f, s1 = 0.f, s2 = 0.f, s3 = 0.f;
  float m0 = -INFINITY, m1 = -INFINITY, m2 = -INFINITY, m3 = -INFINITY;
  #pragma unroll
  for (int t = 0; t < 16; ++t) {
    int tok = __shfl(tok0, 2 * t + half);
    uint2 v = make_uint2(0u, 0u);
    if (tok) v = rows2[(size_t)tok * 32 + laneL];
    float f0 = bf2f((unsigned short)(v.x & 0xFFFF));
    float f1 = bf2f((unsigned short)(v.x >> 16));
    float f2 = bf2f((unsigned short)(v.y & 0xFFFF));
    float f3 = bf2f((unsigned short)(v.y >> 16));
    s0 += f0; s1 += f1; s2 += f2; s3 += f3;
    m0 = fmaxf(m0, f0); m1 = fmaxf(m1, f1);
    m2 = fmaxf(m2, f2); m3 = fmaxf(m3, f3);
  }
  // combine the two token-halves (same dims, different tokens)
  s0 += __shfl_xor(s0, 32); s1 += __shfl_xor(s1, 32);
  s2 += __shfl_xor(s2, 32); s3 += __shfl_xor(s3, 32);
  m0 = fmaxf(m0, __shfl_xor(m0, 32)); m1 = fmaxf(m1, __shfl_xor(m1, 32));
  m2 = fmaxf(m2, __shfl_xor(m2, 32)); m3 = fmaxf(m3, __shfl_xor(m3, 32));

  if (half == 0) {
    uint2* hv = h + (size_t)node * 64;
    hv[laneL]      = make_uint2(pack2bf(s0 * inv, s1 * inv), pack2bf(s2 * inv, s3 * inv));
    hv[32 + laneL] = make_uint2(pack2bf(m0, m1), pack2bf(m2, m3));
  }
}

// ---------------- MFMA GEMM1 ----------------
__global__ __launch_bounds__(256) void k_mm1(const unsigned short* __restrict__ hb,
                                             const unsigned short* __restrict__ Wp,
                                             const float* __restrict__ norm_s,
                                             unsigned short* __restrict__ out) {
  __shared__ unsigned short sA[64 * 256];
  int tid = threadIdx.x;
  int r0 = blockIdx.x * 64;
  #pragma unroll
  for (int it = 0; it < 8; ++it) {
    int idx = it * 256 + tid;
    int r = idx >> 5, kb = idx & 31;
    uint4 v = make_uint4(0, 0, 0, 0);
    int row = r0 + r;
    if (row < N_NODES) v = *(const uint4*)(hb + (size_t)row * 256 + kb * 8);
    *(uint4*)&sA[r * 256 + ((kb ^ (r & 7)) << 3)] = v;
  }
  __syncthreads();

  int w = tid >> 6, lane = tid & 63;
  const short8* W8 = (const short8*)Wp;
  f32x4 acc[4][4];
  #pragma unroll
  for (int i = 0; i < 4; ++i)
    #pragma unroll
    for (int j = 0; j < 4; ++j) acc[i][j] = (f32x4){0.f, 0.f, 0.f, 0.f};

  #pragma unroll
  for (int kt = 0; kt < 8; ++kt) {
    short8 a[4], b[4];
    int kb = kt * 4 + (lane >> 4);
    #pragma unroll
    for (int ri = 0; ri < 4; ++ri) {
      int r = ri * 16 + (lane & 15);
      a[ri] = *(const short8*)&sA[r * 256 + ((kb ^ (r & 7)) << 3)];
    }
    #pragma unroll
    for (int jb = 0; jb < 4; ++jb) b[jb] = W8[(kt * 16 + w * 4 + jb) * 64 + lane];
    #pragma unroll
    for (int ri = 0; ri < 4; ++ri)
      #pragma unroll
      for (int jb = 0; jb < 4; ++jb)
        acc[ri][jb] = __builtin_amdgcn_mfma_f32_16x16x32_bf16(a[ri], b[jb], acc[ri][jb], 0, 0, 0);
  }

  #pragma unroll
  for (int ri = 0; ri < 4; ++ri) {
    #pragma unroll
    for (int rr = 0; rr < 4; ++rr) {
      int row = r0 + ri * 16 + (lane >> 4) * 4 + rr;
      if (row < N_NODES) {
        float ns = norm_s[row];
        #pragma unroll
        for (int jb = 0; jb < 4; ++jb) {
          int col = w * 64 + jb * 16 + (lane & 15);
          out[(size_t)row * 256 + col] = f2bf(acc[ri][jb][rr] * ns);
        }
      }
    }
  }
}

// ---------------- aggregation layer 1: 1 wave = 1 node, uint2/lane ----------------
// lane owns feats 4*lane..4*lane+3 end-to-end; no cross-lane reduce.
__global__ __launch_bounds__(256) void k_agg1(const uint2* __restrict__ rows2, // msgb as uint2 (64/row)
                                              const int* __restrict__ offs,
                                              const int* __restrict__ csr_src,
                                              const float* __restrict__ norm_d,
                                              const float* __restrict__ b1,
                                              uint2* __restrict__ out) {
  int tid = threadIdx.x;
  int w = tid >> 6, lane = tid & 63;
  int node = blockIdx.x * 4 + w;
  int beg = __builtin_amdgcn_readfirstlane(offs[node]);
  int end = __builtin_amdgcn_readfirstlane(offs[node + 1]);

  float a0 = 0.f, a1 = 0.f, a2 = 0.f, a3 = 0.f;
  int e = beg;
  for (; e + 8 <= end; e += 8) {
    int s[8];
    #pragma unroll
    for (int i = 0; i < 8; ++i) s[i] = csr_src[e + i];
    #pragma unroll
    for (int i = 0; i < 8; ++i) {
      uint2 v = rows2[(size_t)s[i] * 64 + lane];
      a0 += bf2f((unsigned short)(v.x & 0xFFFF));
      a1 += bf2f((unsigned short)(v.x >> 16));
      a2 += bf2f((unsigned short)(v.y & 0xFFFF));
      a3 += bf2f((unsigned short)(v.y >> 16));
    }
  }
  for (; e + 4 <= end; e += 4) {
    int s[4];
    #pragma unroll
    for (int i = 0; i < 4; ++i) s[i] = csr_src[e + i];
    #pragma unroll
    for (int i = 0; i < 4; ++i) {
      uint2 v = rows2[(size_t)s[i] * 64 + lane];
      a0 += bf2f((unsigned short)(v.x & 0xFFFF));
      a1 += bf2f((unsigned short)(v.x >> 16));
      a2 += bf2f((unsigned short)(v.y & 0xFFFF));
      a3 += bf2f((unsigned short)(v.y >> 16));
    }
  }
  for (; e < end; ++e) {
    uint2 v = rows2[(size_t)csr_src[e] * 64 + lane];
    a0 += bf2f((unsigned short)(v.x & 0xFFFF));
    a1 += bf2f((unsigned short)(v.x >> 16));
    a2 += bf2f((unsigned short)(v.y & 0xFFFF));
    a3 += bf2f((unsigned short)(v.y >> 16));
  }

  float nd = norm_d[node];
  float4 bb = *(const float4*)&b1[4 * lane];
  float o0 = fmaxf(a0 * nd + bb.x, 0.f);
  float o1 = fmaxf(a1 * nd + bb.y, 0.f);
  float o2 = fmaxf(a2 * nd + bb.z, 0.f);
  float o3 = fmaxf(a3 * nd + bb.w, 0.f);
  out[(size_t)node * 64 + lane] = make_uint2(pack2bf(o0, o1), pack2bf(o2, o3));
}

// ---------------- MFMA GEMM2 ----------------
__global__ __launch_bounds__(256) void k_mm2(const unsigned short* __restrict__ h2b,
                                             const unsigned short* __restrict__ Wp,
                                             const float* __restrict__ norm_s,
                                             unsigned short* __restrict__ out) {
  __shared__ unsigned short sA[64 * 256];
  int tid = threadIdx.x;
  int r0 = blockIdx.x * 64;
  #pragma unroll
  for (int it = 0; it < 8; ++it) {
    int idx = it * 256 + tid;
    int r = idx >> 5, kb = idx & 31;
    uint4 v = make_uint4(0, 0, 0, 0);
    int row = r0 + r;
    if (row < N_NODES) v = *(const uint4*)(h2b + (size_t)row * 256 + kb * 8);
    *(uint4*)&sA[r * 256 + ((kb ^ (r & 7)) << 3)] = v;
  }
  __syncthreads();

  int w = tid >> 6, lane = tid & 63;
  const short8* W8 = (const short8*)Wp;
  f32x4 acc[3];
  #pragma unroll
  for (int j = 0; j < 3; ++j) acc[j] = (f32x4){0.f, 0.f, 0.f, 0.f};

  #pragma unroll
  for (int kt = 0; kt < 8; ++kt) {
    int r = w * 16 + (lane & 15);
    int kb = kt * 4 + (lane >> 4);
    short8 a = *(const short8*)&sA[r * 256 + ((kb ^ (r & 7)) << 3)];
    #pragma unroll
    for (int jb = 0; jb < 3; ++jb) {
      short8 b = W8[(kt * 3 + jb) * 64 + lane];
      acc[jb] = __builtin_amdgcn_mfma_f32_16x16x32_bf16(a, b, acc[jb], 0, 0, 0);
    }
  }

  #pragma unroll
  for (int rr = 0; rr < 4; ++rr) {
    int row = r0 + w * 16 + (lane >> 4) * 4 + rr;
    if (row < N_NODES) {
      float ns = norm_s[row];
      #pragma unroll
      for (int jb = 0; jb < 3; ++jb) {
        int col = jb * 16 + (lane & 15);
        if (col < N_CLASSES) out[(size_t)row * N_CLASSES + col] = f2bf(acc[jb][rr] * ns);
      }
    }
  }
}

// ---------------- aggregation layer 2 (uint loads, 3 edge-slots x 20 lanes) ----------------
__global__ __launch_bounds__(256) void k_agg2(const unsigned int* __restrict__ rows, // hw2b
                                              const int* __restrict__ offs,
                                              const int* __restrict__ csr_src,
                                              const float* __restrict__ norm_d,
                                              const float* __restrict__ b2,
                                              float* __restrict__ out) {
  int tid = threadIdx.x;
  int w = tid >> 6, lane = tid & 63;
  int node = blockIdx.x * 4 + w;
  int slot = lane / 20, fl = lane % 20; // slot 3 idle
  int beg = offs[node], end = offs[node + 1];

  float a0 = 0.f, a1 = 0.f;
  if (slot < 3) {
    for (int e = beg + slot; e < end; e += 3) {
      int s = csr_src[e];
      unsigned int v = rows[(size_t)s * 20 + fl];
      a0 += bf2f((unsigned short)(v & 0xFFFF));
      a1 += bf2f((unsigned short)(v >> 16));
    }
  }
  float p0 = __shfl(a0, lane + 20), p1 = __shfl(a1, lane + 20);
  float q0 = __shfl(a0, lane + 40), q1 = __shfl(a1, lane + 40);
  if (slot == 0) {
    a0 += p0 + q0; a1 += p1 + q1;
    float nd = norm_d[node];
    float o0 = a0 * nd + b2[2 * fl];
    float o1 = a1 * nd + b2[2 * fl + 1];
    *(float2*)&out[(size_t)node * N_CLASSES + 2 * fl] = make_float2(o0, o1);
  }
}

extern "C" void kernel_launch(void* const* d_in, const int* in_sizes, int n_in,
                              void* d_out, int out_size, void* d_ws, size_t ws_size,
                              hipStream_t stream) {
  const int*   feats = (const int*)d_in[0];
  const int*   src   = (const int*)d_in[1];
  const int*   dst   = (const int*)d_in[2];
  const float* emb   = (const float*)d_in[3];
  const float* W1    = (const float*)d_in[4];
  const float* b1    = (const float*)d_in[5];
  const float* W2    = (const float*)d_in[6];
  const float* b2    = (const float*)d_in[7];
  float* out = (float*)d_out;

  char* base = (char*)d_ws;
  size_t off = 0;
  auto alloc = [&](size_t bytes) -> char* {
    char* p = base + off;
    off += (bytes + 255) & ~(size_t)255;
    return p;
  };
  unsigned short* hb      = (unsigned short*)alloc((size_t)N_NODES * IN_FEATS * 2);  // h bf16; reused as h2b
  unsigned short* msgb    = (unsigned short*)alloc((size_t)N_NODES * N_HIDDEN * 2);
  unsigned short* hw2b    = (unsigned short*)alloc((size_t)N_NODES * N_CLASSES * 2);
  unsigned short* emb_b   = (unsigned short*)alloc((size_t)N_TOKENS * EMB_DIM * 2);
  unsigned short* Wp1     = (unsigned short*)alloc((size_t)8 * 16 * 64 * 8 * 2);
  unsigned short* Wp2     = (unsigned short*)alloc((size_t)8 * 3 * 64 * 8 * 2);
  int*   deg_out = (int*)alloc((size_t)3 * N_NODES * 4);
  int*   deg_in  = deg_out + N_NODES;
  int*   cursor  = deg_in + N_NODES;
  float* norm_s  = (float*)alloc((size_t)N_NODES * 4);
  float* norm_d  = (float*)alloc((size_t)N_NODES * 4);
  int*   offs    = (int*)alloc((size_t)(N_NODES + 1) * 4);
  int*   csums   = (int*)alloc((size_t)N_CHUNKS * 4);
  int*   csr_src = (int*)alloc((size_t)N_EDGES * 4);

  hipMemsetAsync(deg_out, 0, (size_t)3 * N_NODES * 4, stream);

  int eb = (N_EDGES + 255) / 256;
  int nb = (N_NODES + 255) / 256;
  k_emb2bf<<<2048, 256, 0, stream>>>(emb, emb_b);
  k_packW1<<<32, 256, 0, stream>>>(W1, Wp1);
  k_packW2<<<6, 256, 0, stream>>>(W2, Wp2);
  k_degree<<<eb, 256, 0, stream>>>(src, dst, deg_out, deg_in);
  k_norm<<<nb, 256, 0, stream>>>(deg_out, deg_in, norm_s, norm_d);
  k_chunksum<<<N_CHUNKS, SCAN_CHUNK, 0, stream>>>(deg_in, csums);
  k_topscan<<<1, 64, 0, stream>>>(csums);
  k_chunkscan<<<N_CHUNKS, SCAN_CHUNK, 0, stream>>>(deg_in, csums, offs);
  k_csr_fill<<<eb, 256, 0, stream>>>(src, dst, offs, cursor, csr_src);

  int gemm_blocks = (N_NODES + 63) / 64; // 782
  k_embed<<<N_NODES / 4, 256, 0, stream>>>(feats, (const uint2*)emb_b, (uint2*)hb);
  k_mm1<<<gemm_blocks, 256, 0, stream>>>(hb, Wp1, norm_s, msgb);
  k_agg1<<<N_NODES / 4, 256, 0, stream>>>((const uint2*)msgb, offs, csr_src, norm_d, b1, (uint2*)hb);
  k_mm2<<<gemm_blocks, 256, 0, stream>>>(hb, Wp2, norm_s, hw2b);
  k_agg2<<<N_NODES / 4, 256, 0, stream>>>((const unsigned int*)hw2b, offs, csr_src, norm_d, b2, out);
}

// Round 7
// 269.718 us; speedup vs baseline: 2.1094x; 1.1409x over previous
//
#include <hip/hip_runtime.h>
#include <math.h>

#define N_NODES 50000
#define SEQ_LEN 32
#define EMB_DIM 128
#define IN_FEATS 256
#define N_HIDDEN 256
#define N_CLASSES 40
#define N_EDGES 800000
#define N_TOKENS 100000

#define SLOT 64          // padded-CSR slot per node (max in-degree << 64)
#define REP 8            // deg_out histogram replicas
#define REP_STRIDE 50048 // int stride per replica (line-spread)

typedef short short8 __attribute__((ext_vector_type(8)));
typedef float f32x4 __attribute__((ext_vector_type(4)));

__device__ __forceinline__ unsigned short f2bf(float x) {
  unsigned int u = __float_as_uint(x);
  unsigned int r = (u + 0x7FFFu + ((u >> 16) & 1u)) >> 16; // RTNE
  return (unsigned short)r;
}
__device__ __forceinline__ float bf2f(unsigned short s) {
  return __uint_as_float((unsigned int)s << 16);
}
__device__ __forceinline__ unsigned int pack2bf(float a, float b) {
  return (unsigned int)f2bf(a) | ((unsigned int)f2bf(b) << 16);
}

// ---------------- fused graph build: padded CSR + replicated deg_out ----------------
// 4 edges/thread via int4. cursor[d] ends as deg_in[d]; csr_pad[d*SLOT + p] = src.
__global__ __launch_bounds__(256) void k_graph(const int* __restrict__ src,
                                               const int* __restrict__ dst,
                                               int* __restrict__ cursor,
                                               int* __restrict__ deg8,
                                               int* __restrict__ csr_pad) {
  int i = blockIdx.x * 256 + threadIdx.x; // quad index
  if (i * 4 >= N_EDGES) return;
  int r = ((threadIdx.x >> 6) + (blockIdx.x << 2)) & (REP - 1);
  int* dr = deg8 + r * REP_STRIDE;
  int4 s4 = ((const int4*)src)[i];
  int4 d4 = ((const int4*)dst)[i];
  int p;
  p = atomicAdd(&cursor[d4.x], 1); csr_pad[(size_t)d4.x * SLOT + p] = s4.x;
  p = atomicAdd(&cursor[d4.y], 1); csr_pad[(size_t)d4.y * SLOT + p] = s4.y;
  p = atomicAdd(&cursor[d4.z], 1); csr_pad[(size_t)d4.z * SLOT + p] = s4.z;
  p = atomicAdd(&cursor[d4.w], 1); csr_pad[(size_t)d4.w * SLOT + p] = s4.w;
  atomicAdd(&dr[s4.x], 1);
  atomicAdd(&dr[s4.y], 1);
  atomicAdd(&dr[s4.z], 1);
  atomicAdd(&dr[s4.w], 1);
}

// ---------------- norms from replicated deg_out + cursor(=deg_in) ----------------
__global__ __launch_bounds__(256) void k_norm(const int* __restrict__ deg8,
                                              const int* __restrict__ cursor,
                                              float* __restrict__ norm_s,
                                              float* __restrict__ norm_d) {
  int i = blockIdx.x * 256 + threadIdx.x;
  if (i < N_NODES) {
    int dsum = 0;
    #pragma unroll
    for (int r = 0; r < REP; ++r) dsum += deg8[r * REP_STRIDE + i];
    norm_s[i] = 1.0f / sqrtf((float)max(dsum, 1));
    norm_d[i] = 1.0f / sqrtf((float)max(cursor[i], 1));
  }
}

// ---------------- emb table fp32 -> bf16 ----------------
__global__ __launch_bounds__(256) void k_emb2bf(const float* __restrict__ emb,
                                                unsigned short* __restrict__ emb_b) {
  const int total = N_TOKENS * EMB_DIM / 4;
  for (int i = blockIdx.x * 256 + threadIdx.x; i < total; i += gridDim.x * 256) {
    float4 v = ((const float4*)emb)[i];
    ushort4 o;
    o.x = f2bf(v.x); o.y = f2bf(v.y); o.z = f2bf(v.z); o.w = f2bf(v.w);
    ((ushort4*)emb_b)[i] = o;
  }
}

// ---------------- W packs ----------------
__global__ __launch_bounds__(256) void k_packW1(const float* __restrict__ W,
                                                unsigned short* __restrict__ Wp) {
  int g = blockIdx.x * 256 + threadIdx.x; // 8192 total
  int lane = g & 63, jb = (g >> 6) & 15, kt = g >> 10;
  int col = jb * 16 + (lane & 15);
  int kbase = kt * 32 + (lane >> 4) * 8;
  unsigned short* o = Wp + (size_t)g * 8;
  #pragma unroll
  for (int e = 0; e < 8; ++e) o[e] = f2bf(W[(size_t)(kbase + e) * N_HIDDEN + col]);
}

__global__ __launch_bounds__(256) void k_packW2(const float* __restrict__ W,
                                                unsigned short* __restrict__ Wp) {
  int g = blockIdx.x * 256 + threadIdx.x; // 1536 total
  if (g >= 8 * 3 * 64) return;
  int lane = g & 63, jb = (g >> 6) % 3, kt = g / (3 * 64);
  int col = jb * 16 + (lane & 15);
  int kbase = kt * 32 + (lane >> 4) * 8;
  unsigned short* o = Wp + (size_t)g * 8;
  #pragma unroll
  for (int e = 0; e < 8; ++e)
    o[e] = (col < N_CLASSES) ? f2bf(W[(size_t)(kbase + e) * N_CLASSES + col]) : (unsigned short)0;
}

// ---------------- embedding + pooling: 1 wave = 1 node, uint2/lane ----------------
__global__ __launch_bounds__(256) void k_embed(const int* __restrict__ feats,
                                               const uint2* __restrict__ rows2, // emb_b as uint2 (32/row)
                                               uint2* __restrict__ h) {        // h as uint2 (64/row)
  int tid = threadIdx.x;
  int w = tid >> 6, lane = tid & 63;
  int node = blockIdx.x * 4 + w;
  int laneL = lane & 31, half = lane >> 5;

  int tok0 = feats[(size_t)node * SEQ_LEN + laneL];
  unsigned long long m = __ballot(laneL < 32 && tok0 != 0);
  int cnt = (int)__popcll(m & 0xFFFFFFFFull);
  float inv = 1.0f / (float)max(cnt, 1);

  float s0 = 0.f, s1 = 0.f, s2 = 0.f, s3 = 0.f;
  float m0 = -INFINITY, m1 = -INFINITY, m2 = -INFINITY, m3 = -INFINITY;
  #pragma unroll
  for (int t = 0; t < 16; ++t) {
    int tok = __shfl(tok0, 2 * t + half);
    uint2 v = make_uint2(0u, 0u);
    if (tok) v = rows2[(size_t)tok * 32 + laneL];
    float f0 = bf2f((unsigned short)(v.x & 0xFFFF));
    float f1 = bf2f((unsigned short)(v.x >> 16));
    float f2 = bf2f((unsigned short)(v.y & 0xFFFF));
    float f3 = bf2f((unsigned short)(v.y >> 16));
    s0 += f0; s1 += f1; s2 += f2; s3 += f3;
    m0 = fmaxf(m0, f0); m1 = fmaxf(m1, f1);
    m2 = fmaxf(m2, f2); m3 = fmaxf(m3, f3);
  }
  s0 += __shfl_xor(s0, 32); s1 += __shfl_xor(s1, 32);
  s2 += __shfl_xor(s2, 32); s3 += __shfl_xor(s3, 32);
  m0 = fmaxf(m0, __shfl_xor(m0, 32)); m1 = fmaxf(m1, __shfl_xor(m1, 32));
  m2 = fmaxf(m2, __shfl_xor(m2, 32)); m3 = fmaxf(m3, __shfl_xor(m3, 32));

  if (half == 0) {
    uint2* hv = h + (size_t)node * 64;
    hv[laneL]      = make_uint2(pack2bf(s0 * inv, s1 * inv), pack2bf(s2 * inv, s3 * inv));
    hv[32 + laneL] = make_uint2(pack2bf(m0, m1), pack2bf(m2, m3));
  }
}

// ---------------- MFMA GEMM1 ----------------
__global__ __launch_bounds__(256) void k_mm1(const unsigned short* __restrict__ hb,
                                             const unsigned short* __restrict__ Wp,
                                             const float* __restrict__ norm_s,
                                             unsigned short* __restrict__ out) {
  __shared__ unsigned short sA[64 * 256];
  int tid = threadIdx.x;
  int r0 = blockIdx.x * 64;
  #pragma unroll
  for (int it = 0; it < 8; ++it) {
    int idx = it * 256 + tid;
    int r = idx >> 5, kb = idx & 31;
    uint4 v = make_uint4(0, 0, 0, 0);
    int row = r0 + r;
    if (row < N_NODES) v = *(const uint4*)(hb + (size_t)row * 256 + kb * 8);
    *(uint4*)&sA[r * 256 + ((kb ^ (r & 7)) << 3)] = v;
  }
  __syncthreads();

  int w = tid >> 6, lane = tid & 63;
  const short8* W8 = (const short8*)Wp;
  f32x4 acc[4][4];
  #pragma unroll
  for (int i = 0; i < 4; ++i)
    #pragma unroll
    for (int j = 0; j < 4; ++j) acc[i][j] = (f32x4){0.f, 0.f, 0.f, 0.f};

  #pragma unroll
  for (int kt = 0; kt < 8; ++kt) {
    short8 a[4], b[4];
    int kb = kt * 4 + (lane >> 4);
    #pragma unroll
    for (int ri = 0; ri < 4; ++ri) {
      int r = ri * 16 + (lane & 15);
      a[ri] = *(const short8*)&sA[r * 256 + ((kb ^ (r & 7)) << 3)];
    }
    #pragma unroll
    for (int jb = 0; jb < 4; ++jb) b[jb] = W8[(kt * 16 + w * 4 + jb) * 64 + lane];
    #pragma unroll
    for (int ri = 0; ri < 4; ++ri)
      #pragma unroll
      for (int jb = 0; jb < 4; ++jb)
        acc[ri][jb] = __builtin_amdgcn_mfma_f32_16x16x32_bf16(a[ri], b[jb], acc[ri][jb], 0, 0, 0);
  }

  #pragma unroll
  for (int ri = 0; ri < 4; ++ri) {
    #pragma unroll
    for (int rr = 0; rr < 4; ++rr) {
      int row = r0 + ri * 16 + (lane >> 4) * 4 + rr;
      if (row < N_NODES) {
        float ns = norm_s[row];
        #pragma unroll
        for (int jb = 0; jb < 4; ++jb) {
          int col = w * 64 + jb * 16 + (lane & 15);
          out[(size_t)row * 256 + col] = f2bf(acc[ri][jb][rr] * ns);
        }
      }
    }
  }
}

// ---------------- aggregation layer 1: 1 wave = 1 node, padded CSR ----------------
__global__ __launch_bounds__(256) void k_agg1(const uint2* __restrict__ rows2, // msgb as uint2 (64/row)
                                              const int* __restrict__ cursor,
                                              const int* __restrict__ csr_pad,
                                              const float* __restrict__ norm_d,
                                              const float* __restrict__ b1,
                                              uint2* __restrict__ out) {
  int tid = threadIdx.x;
  int w = tid >> 6, lane = tid & 63;
  int node = blockIdx.x * 4 + w;
  int cnt = __builtin_amdgcn_readfirstlane(cursor[node]);
  const int* csr = csr_pad + (size_t)node * SLOT;

  float a0 = 0.f, a1 = 0.f, a2 = 0.f, a3 = 0.f;
  int e = 0;
  for (; e + 8 <= cnt; e += 8) {
    int s[8];
    #pragma unroll
    for (int i = 0; i < 8; ++i) s[i] = csr[e + i];
    #pragma unroll
    for (int i = 0; i < 8; ++i) {
      uint2 v = rows2[(size_t)s[i] * 64 + lane];
      a0 += bf2f((unsigned short)(v.x & 0xFFFF));
      a1 += bf2f((unsigned short)(v.x >> 16));
      a2 += bf2f((unsigned short)(v.y & 0xFFFF));
      a3 += bf2f((unsigned short)(v.y >> 16));
    }
  }
  for (; e + 4 <= cnt; e += 4) {
    int s[4];
    #pragma unroll
    for (int i = 0; i < 4; ++i) s[i] = csr[e + i];
    #pragma unroll
    for (int i = 0; i < 4; ++i) {
      uint2 v = rows2[(size_t)s[i] * 64 + lane];
      a0 += bf2f((unsigned short)(v.x & 0xFFFF));
      a1 += bf2f((unsigned short)(v.x >> 16));
      a2 += bf2f((unsigned short)(v.y & 0xFFFF));
      a3 += bf2f((unsigned short)(v.y >> 16));
    }
  }
  for (; e < cnt; ++e) {
    uint2 v = rows2[(size_t)csr[e] * 64 + lane];
    a0 += bf2f((unsigned short)(v.x & 0xFFFF));
    a1 += bf2f((unsigned short)(v.x >> 16));
    a2 += bf2f((unsigned short)(v.y & 0xFFFF));
    a3 += bf2f((unsigned short)(v.y >> 16));
  }

  float nd = norm_d[node];
  float4 bb = *(const float4*)&b1[4 * lane];
  float o0 = fmaxf(a0 * nd + bb.x, 0.f);
  float o1 = fmaxf(a1 * nd + bb.y, 0.f);
  float o2 = fmaxf(a2 * nd + bb.z, 0.f);
  float o3 = fmaxf(a3 * nd + bb.w, 0.f);
  out[(size_t)node * 64 + lane] = make_uint2(pack2bf(o0, o1), pack2bf(o2, o3));
}

// ---------------- MFMA GEMM2 ----------------
__global__ __launch_bounds__(256) void k_mm2(const unsigned short* __restrict__ h2b,
                                             const unsigned short* __restrict__ Wp,
                                             const float* __restrict__ norm_s,
                                             unsigned short* __restrict__ out) {
  __shared__ unsigned short sA[64 * 256];
  int tid = threadIdx.x;
  int r0 = blockIdx.x * 64;
  #pragma unroll
  for (int it = 0; it < 8; ++it) {
    int idx = it * 256 + tid;
    int r = idx >> 5, kb = idx & 31;
    uint4 v = make_uint4(0, 0, 0, 0);
    int row = r0 + r;
    if (row < N_NODES) v = *(const uint4*)(h2b + (size_t)row * 256 + kb * 8);
    *(uint4*)&sA[r * 256 + ((kb ^ (r & 7)) << 3)] = v;
  }
  __syncthreads();

  int w = tid >> 6, lane = tid & 63;
  const short8* W8 = (const short8*)Wp;
  f32x4 acc[3];
  #pragma unroll
  for (int j = 0; j < 3; ++j) acc[j] = (f32x4){0.f, 0.f, 0.f, 0.f};

  #pragma unroll
  for (int kt = 0; kt < 8; ++kt) {
    int r = w * 16 + (lane & 15);
    int kb = kt * 4 + (lane >> 4);
    short8 a = *(const short8*)&sA[r * 256 + ((kb ^ (r & 7)) << 3)];
    #pragma unroll
    for (int jb = 0; jb < 3; ++jb) {
      short8 b = W8[(kt * 3 + jb) * 64 + lane];
      acc[jb] = __builtin_amdgcn_mfma_f32_16x16x32_bf16(a, b, acc[jb], 0, 0, 0);
    }
  }

  #pragma unroll
  for (int rr = 0; rr < 4; ++rr) {
    int row = r0 + w * 16 + (lane >> 4) * 4 + rr;
    if (row < N_NODES) {
      float ns = norm_s[row];
      #pragma unroll
      for (int jb = 0; jb < 3; ++jb) {
        int col = jb * 16 + (lane & 15);
        if (col < N_CLASSES) out[(size_t)row * N_CLASSES + col] = f2bf(acc[jb][rr] * ns);
      }
    }
  }
}

// ---------------- aggregation layer 2 (padded CSR, 3 edge-slots x 20 lanes) ----------------
__global__ __launch_bounds__(256) void k_agg2(const unsigned int* __restrict__ rows, // hw2b
                                              const int* __restrict__ cursor,
                                              const int* __restrict__ csr_pad,
                                              const float* __restrict__ norm_d,
                                              const float* __restrict__ b2,
                                              float* __restrict__ out) {
  int tid = threadIdx.x;
  int w = tid >> 6, lane = tid & 63;
  int node = blockIdx.x * 4 + w;
  int slot = lane / 20, fl = lane % 20; // slot 3 idle
  int cnt = __builtin_amdgcn_readfirstlane(cursor[node]);
  const int* csr = csr_pad + (size_t)node * SLOT;

  float a0 = 0.f, a1 = 0.f;
  if (slot < 3) {
    for (int e = slot; e < cnt; e += 3) {
      int s = csr[e];
      unsigned int v = rows[(size_t)s * 20 + fl];
      a0 += bf2f((unsigned short)(v & 0xFFFF));
      a1 += bf2f((unsigned short)(v >> 16));
    }
  }
  float p0 = __shfl(a0, lane + 20), p1 = __shfl(a1, lane + 20);
  float q0 = __shfl(a0, lane + 40), q1 = __shfl(a1, lane + 40);
  if (slot == 0) {
    a0 += p0 + q0; a1 += p1 + q1;
    float nd = norm_d[node];
    float o0 = a0 * nd + b2[2 * fl];
    float o1 = a1 * nd + b2[2 * fl + 1];
    *(float2*)&out[(size_t)node * N_CLASSES + 2 * fl] = make_float2(o0, o1);
  }
}

extern "C" void kernel_launch(void* const* d_in, const int* in_sizes, int n_in,
                              void* d_out, int out_size, void* d_ws, size_t ws_size,
                              hipStream_t stream) {
  const int*   feats = (const int*)d_in[0];
  const int*   src   = (const int*)d_in[1];
  const int*   dst   = (const int*)d_in[2];
  const float* emb   = (const float*)d_in[3];
  const float* W1    = (const float*)d_in[4];
  const float* b1    = (const float*)d_in[5];
  const float* W2    = (const float*)d_in[6];
  const float* b2    = (const float*)d_in[7];
  float* out = (float*)d_out;

  char* base = (char*)d_ws;
  size_t off = 0;
  auto alloc = [&](size_t bytes) -> char* {
    char* p = base + off;
    off += (bytes + 255) & ~(size_t)255;
    return p;
  };
  unsigned short* hb      = (unsigned short*)alloc((size_t)N_NODES * IN_FEATS * 2);  // h bf16; reused as h2b
  unsigned short* msgb    = (unsigned short*)alloc((size_t)N_NODES * N_HIDDEN * 2);
  unsigned short* hw2b    = (unsigned short*)alloc((size_t)N_NODES * N_CLASSES * 2);
  unsigned short* emb_b   = (unsigned short*)alloc((size_t)N_TOKENS * EMB_DIM * 2);
  unsigned short* Wp1     = (unsigned short*)alloc((size_t)8 * 16 * 64 * 8 * 2);
  unsigned short* Wp2     = (unsigned short*)alloc((size_t)8 * 3 * 64 * 8 * 2);
  int*   cursor  = (int*)alloc((size_t)(REP + 1) * REP_STRIDE * 4); // cursor | deg8[8]
  int*   deg8    = cursor + REP_STRIDE;
  float* norm_s  = (float*)alloc((size_t)N_NODES * 4);
  float* norm_d  = (float*)alloc((size_t)N_NODES * 4);
  int*   csr_pad = (int*)alloc((size_t)N_NODES * SLOT * 4); // 12.8MB

  hipMemsetAsync(cursor, 0, (size_t)(REP + 1) * REP_STRIDE * 4, stream);

  int nb = (N_NODES + 255) / 256;
  k_emb2bf<<<2048, 256, 0, stream>>>(emb, emb_b);
  k_packW1<<<32, 256, 0, stream>>>(W1, Wp1);
  k_packW2<<<6, 256, 0, stream>>>(W2, Wp2);
  k_graph<<<(N_EDGES / 4 + 255) / 256, 256, 0, stream>>>(src, dst, cursor, deg8, csr_pad);
  k_norm<<<nb, 256, 0, stream>>>(deg8, cursor, norm_s, norm_d);

  int gemm_blocks = (N_NODES + 63) / 64; // 782
  k_embed<<<N_NODES / 4, 256, 0, stream>>>(feats, (const uint2*)emb_b, (uint2*)hb);
  k_mm1<<<gemm_blocks, 256, 0, stream>>>(hb, Wp1, norm_s, msgb);
  k_agg1<<<N_NODES / 4, 256, 0, stream>>>((const uint2*)msgb, cursor, csr_pad, norm_d, b1, (uint2*)hb);
  k_mm2<<<gemm_blocks, 256, 0, stream>>>(hb, Wp2, norm_s, hw2b);
  k_agg2<<<N_NODES / 4, 256, 0, stream>>>((const unsigned int*)hw2b, cursor, csr_pad, norm_d, b2, out);
}

// Round 8
// 230.269 us; speedup vs baseline: 2.4708x; 1.1713x over previous
//
#include <hip/hip_runtime.h>
#include <math.h>

#define N_NODES 50000
#define SEQ_LEN 32
#define EMB_DIM 128
#define IN_FEATS 256
#define N_HIDDEN 256
#define N_CLASSES 40
#define N_EDGES 800000
#define N_TOKENS 100000

#define SLOT 64          // padded-CSR slots per node (max in-degree << 64; verified by prior rounds)
#define NBIN 196         // ceil(50000/256) bins of 256 nodes
#define BINCAP 4608      // mean 4096 + 8 sigma
#define EPB 4000         // edges per binA block (200 blocks exactly)

typedef short short8 __attribute__((ext_vector_type(8)));
typedef float f32x4 __attribute__((ext_vector_type(4)));

__device__ __forceinline__ unsigned short f2bf(float x) {
  unsigned int u = __float_as_uint(x);
  unsigned int r = (u + 0x7FFFu + ((u >> 16) & 1u)) >> 16; // RTNE
  return (unsigned short)r;
}
__device__ __forceinline__ float bf2f(unsigned short s) {
  return __uint_as_float((unsigned int)s << 16);
}
__device__ __forceinline__ unsigned int pack2bf(float a, float b) {
  return (unsigned int)f2bf(a) | ((unsigned int)f2bf(b) << 16);
}

// ---------------- binA: LDS-histogram edges into dst-bins + src-bins ----------------
__global__ __launch_bounds__(256) void k_binA(const int* __restrict__ src,
                                              const int* __restrict__ dst,
                                              int* __restrict__ gcntD,
                                              int* __restrict__ gcntS,
                                              unsigned int* __restrict__ dbin,
                                              unsigned char* __restrict__ sbin) {
  __shared__ int cntD[NBIN], cntS[NBIN], baseD[NBIN], baseS[NBIN];
  int tid = threadIdx.x;
  if (tid < NBIN) { cntD[tid] = 0; cntS[tid] = 0; }
  __syncthreads();
  int e0 = blockIdx.x * EPB;
  for (int j = tid; j < EPB; j += 256) {
    int d = dst[e0 + j], s = src[e0 + j];
    atomicAdd(&cntD[d >> 8], 1);
    atomicAdd(&cntS[s >> 8], 1);
  }
  __syncthreads();
  if (tid < NBIN) {
    baseD[tid] = atomicAdd(&gcntD[tid], cntD[tid]);
    baseS[tid] = atomicAdd(&gcntS[tid], cntS[tid]);
    cntD[tid] = 0;
    cntS[tid] = 0;
  }
  __syncthreads();
  for (int j = tid; j < EPB; j += 256) {
    int d = dst[e0 + j], s = src[e0 + j];
    int bd = d >> 8, bs = s >> 8;
    int od = atomicAdd(&cntD[bd], 1);
    int pd = baseD[bd] + od;
    if (pd < BINCAP) dbin[(size_t)bd * BINCAP + pd] = ((unsigned int)s << 8) | (unsigned int)(d & 255);
    int os = atomicAdd(&cntS[bs], 1);
    int ps = baseS[bs] + os;
    if (ps < BINCAP) sbin[(size_t)bs * BINCAP + ps] = (unsigned char)(s & 255);
  }
}

// ---------------- binB: per-bin CSR build (no global atomics) ----------------
__global__ __launch_bounds__(256) void k_binB(const unsigned int* __restrict__ dbin,
                                              const int* __restrict__ gcntD,
                                              int* __restrict__ cursor,
                                              int* __restrict__ csr_pad) {
  __shared__ int cnt[256];
  int tid = threadIdx.x, b = blockIdx.x;
  cnt[tid] = 0;
  __syncthreads();
  int n = min(gcntD[b], BINCAP);
  const unsigned int* bb = dbin + (size_t)b * BINCAP;
  for (int j = tid; j < n; j += 256) {
    unsigned int e = bb[j];
    int lo = e & 255;
    int slot = atomicAdd(&cnt[lo], 1);
    if (slot < SLOT) csr_pad[(size_t)(b * 256 + lo) * SLOT + slot] = (int)(e >> 8);
  }
  __syncthreads();
  int node = b * 256 + tid;
  if (node < N_NODES) cursor[node] = min(cnt[tid], SLOT);
}

// ---------------- degout: per-bin byte histogram (no global atomics) ----------------
__global__ __launch_bounds__(256) void k_degout(const unsigned char* __restrict__ sbin,
                                                const int* __restrict__ gcntS,
                                                int* __restrict__ deg_out) {
  __shared__ int cnt[256];
  int tid = threadIdx.x, b = blockIdx.x;
  cnt[tid] = 0;
  __syncthreads();
  int n = min(gcntS[b], BINCAP);
  const unsigned char* bb = sbin + (size_t)b * BINCAP;
  for (int j = tid; j < n; j += 256) atomicAdd(&cnt[bb[j]], 1);
  __syncthreads();
  int node = b * 256 + tid;
  if (node < N_NODES) deg_out[node] = cnt[tid];
}

// ---------------- norms ----------------
__global__ __launch_bounds__(256) void k_norm(const int* __restrict__ deg_out,
                                              const int* __restrict__ cursor,
                                              float* __restrict__ norm_s,
                                              float* __restrict__ norm_d) {
  int i = blockIdx.x * 256 + threadIdx.x;
  if (i < N_NODES) {
    norm_s[i] = 1.0f / sqrtf((float)max(deg_out[i], 1));
    norm_d[i] = 1.0f / sqrtf((float)max(cursor[i], 1));
  }
}

// ---------------- emb table fp32 -> bf16 ----------------
__global__ __launch_bounds__(256) void k_emb2bf(const float* __restrict__ emb,
                                                unsigned short* __restrict__ emb_b) {
  const int total = N_TOKENS * EMB_DIM / 4;
  for (int i = blockIdx.x * 256 + threadIdx.x; i < total; i += gridDim.x * 256) {
    float4 v = ((const float4*)emb)[i];
    ushort4 o;
    o.x = f2bf(v.x); o.y = f2bf(v.y); o.z = f2bf(v.z); o.w = f2bf(v.w);
    ((ushort4*)emb_b)[i] = o;
  }
}

// ---------------- W packs ----------------
__global__ __launch_bounds__(256) void k_packW1(const float* __restrict__ W,
                                                unsigned short* __restrict__ Wp) {
  int g = blockIdx.x * 256 + threadIdx.x; // 8192 total
  int lane = g & 63, jb = (g >> 6) & 15, kt = g >> 10;
  int col = jb * 16 + (lane & 15);
  int kbase = kt * 32 + (lane >> 4) * 8;
  unsigned short* o = Wp + (size_t)g * 8;
  #pragma unroll
  for (int e = 0; e < 8; ++e) o[e] = f2bf(W[(size_t)(kbase + e) * N_HIDDEN + col]);
}

__global__ __launch_bounds__(256) void k_packW2(const float* __restrict__ W,
                                                unsigned short* __restrict__ Wp) {
  int g = blockIdx.x * 256 + threadIdx.x; // 1536 total
  if (g >= 8 * 3 * 64) return;
  int lane = g & 63, jb = (g >> 6) % 3, kt = g / (3 * 64);
  int col = jb * 16 + (lane & 15);
  int kbase = kt * 32 + (lane >> 4) * 8;
  unsigned short* o = Wp + (size_t)g * 8;
  #pragma unroll
  for (int e = 0; e < 8; ++e)
    o[e] = (col < N_CLASSES) ? f2bf(W[(size_t)(kbase + e) * N_CLASSES + col]) : (unsigned short)0;
}

// ---------------- embedding + pooling: 1 wave = 1 node, uint2/lane ----------------
__global__ __launch_bounds__(256) void k_embed(const int* __restrict__ feats,
                                               const uint2* __restrict__ rows2, // emb_b as uint2 (32/row)
                                               uint2* __restrict__ h) {        // h as uint2 (64/row)
  int tid = threadIdx.x;
  int w = tid >> 6, lane = tid & 63;
  int node = blockIdx.x * 4 + w;
  int laneL = lane & 31, half = lane >> 5;

  int tok0 = feats[(size_t)node * SEQ_LEN + laneL];
  unsigned long long m = __ballot(laneL < 32 && tok0 != 0);
  int cnt = (int)__popcll(m & 0xFFFFFFFFull);
  float inv = 1.0f / (float)max(cnt, 1);

  float s0 = 0.f, s1 = 0.f, s2 = 0.f, s3 = 0.f;
  float m0 = -INFINITY, m1 = -INFINITY, m2 = -INFINITY, m3 = -INFINITY;
  #pragma unroll
  for (int t = 0; t < 16; ++t) {
    int tok = __shfl(tok0, 2 * t + half);
    uint2 v = make_uint2(0u, 0u);
    if (tok) v = rows2[(size_t)tok * 32 + laneL];
    float f0 = bf2f((unsigned short)(v.x & 0xFFFF));
    float f1 = bf2f((unsigned short)(v.x >> 16));
    float f2 = bf2f((unsigned short)(v.y & 0xFFFF));
    float f3 = bf2f((unsigned short)(v.y >> 16));
    s0 += f0; s1 += f1; s2 += f2; s3 += f3;
    m0 = fmaxf(m0, f0); m1 = fmaxf(m1, f1);
    m2 = fmaxf(m2, f2); m3 = fmaxf(m3, f3);
  }
  s0 += __shfl_xor(s0, 32); s1 += __shfl_xor(s1, 32);
  s2 += __shfl_xor(s2, 32); s3 += __shfl_xor(s3, 32);
  m0 = fmaxf(m0, __shfl_xor(m0, 32)); m1 = fmaxf(m1, __shfl_xor(m1, 32));
  m2 = fmaxf(m2, __shfl_xor(m2, 32)); m3 = fmaxf(m3, __shfl_xor(m3, 32));

  if (half == 0) {
    uint2* hv = h + (size_t)node * 64;
    hv[laneL]      = make_uint2(pack2bf(s0 * inv, s1 * inv), pack2bf(s2 * inv, s3 * inv));
    hv[32 + laneL] = make_uint2(pack2bf(m0, m1), pack2bf(m2, m3));
  }
}

// ---------------- MFMA GEMM1 ----------------
__global__ __launch_bounds__(256) void k_mm1(const unsigned short* __restrict__ hb,
                                             const unsigned short* __restrict__ Wp,
                                             const float* __restrict__ norm_s,
                                             unsigned short* __restrict__ out) {
  __shared__ unsigned short sA[64 * 256];
  int tid = threadIdx.x;
  int r0 = blockIdx.x * 64;
  #pragma unroll
  for (int it = 0; it < 8; ++it) {
    int idx = it * 256 + tid;
    int r = idx >> 5, kb = idx & 31;
    uint4 v = make_uint4(0, 0, 0, 0);
    int row = r0 + r;
    if (row < N_NODES) v = *(const uint4*)(hb + (size_t)row * 256 + kb * 8);
    *(uint4*)&sA[r * 256 + ((kb ^ (r & 7)) << 3)] = v;
  }
  __syncthreads();

  int w = tid >> 6, lane = tid & 63;
  const short8* W8 = (const short8*)Wp;
  f32x4 acc[4][4];
  #pragma unroll
  for (int i = 0; i < 4; ++i)
    #pragma unroll
    for (int j = 0; j < 4; ++j) acc[i][j] = (f32x4){0.f, 0.f, 0.f, 0.f};

  #pragma unroll
  for (int kt = 0; kt < 8; ++kt) {
    short8 a[4], b[4];
    int kb = kt * 4 + (lane >> 4);
    #pragma unroll
    for (int ri = 0; ri < 4; ++ri) {
      int r = ri * 16 + (lane & 15);
      a[ri] = *(const short8*)&sA[r * 256 + ((kb ^ (r & 7)) << 3)];
    }
    #pragma unroll
    for (int jb = 0; jb < 4; ++jb) b[jb] = W8[(kt * 16 + w * 4 + jb) * 64 + lane];
    #pragma unroll
    for (int ri = 0; ri < 4; ++ri)
      #pragma unroll
      for (int jb = 0; jb < 4; ++jb)
        acc[ri][jb] = __builtin_amdgcn_mfma_f32_16x16x32_bf16(a[ri], b[jb], acc[ri][jb], 0, 0, 0);
  }

  #pragma unroll
  for (int ri = 0; ri < 4; ++ri) {
    #pragma unroll
    for (int rr = 0; rr < 4; ++rr) {
      int row = r0 + ri * 16 + (lane >> 4) * 4 + rr;
      if (row < N_NODES) {
        float ns = norm_s[row];
        #pragma unroll
        for (int jb = 0; jb < 4; ++jb) {
          int col = w * 64 + jb * 16 + (lane & 15);
          out[(size_t)row * 256 + col] = f2bf(acc[ri][jb][rr] * ns);
        }
      }
    }
  }
}

// ---------------- aggregation layer 1: 1 wave = 1 node, padded CSR ----------------
__global__ __launch_bounds__(256) void k_agg1(const uint2* __restrict__ rows2, // msgb as uint2 (64/row)
                                              const int* __restrict__ cursor,
                                              const int* __restrict__ csr_pad,
                                              const float* __restrict__ norm_d,
                                              const float* __restrict__ b1,
                                              uint2* __restrict__ out) {
  int tid = threadIdx.x;
  int w = tid >> 6, lane = tid & 63;
  int node = blockIdx.x * 4 + w;
  int cnt = __builtin_amdgcn_readfirstlane(cursor[node]);
  const int* csr = csr_pad + (size_t)node * SLOT;

  float a0 = 0.f, a1 = 0.f, a2 = 0.f, a3 = 0.f;
  int e = 0;
  for (; e + 8 <= cnt; e += 8) {
    int s[8];
    #pragma unroll
    for (int i = 0; i < 8; ++i) s[i] = csr[e + i];
    #pragma unroll
    for (int i = 0; i < 8; ++i) {
      uint2 v = rows2[(size_t)s[i] * 64 + lane];
      a0 += bf2f((unsigned short)(v.x & 0xFFFF));
      a1 += bf2f((unsigned short)(v.x >> 16));
      a2 += bf2f((unsigned short)(v.y & 0xFFFF));
      a3 += bf2f((unsigned short)(v.y >> 16));
    }
  }
  for (; e + 4 <= cnt; e += 4) {
    int s[4];
    #pragma unroll
    for (int i = 0; i < 4; ++i) s[i] = csr[e + i];
    #pragma unroll
    for (int i = 0; i < 4; ++i) {
      uint2 v = rows2[(size_t)s[i] * 64 + lane];
      a0 += bf2f((unsigned short)(v.x & 0xFFFF));
      a1 += bf2f((unsigned short)(v.x >> 16));
      a2 += bf2f((unsigned short)(v.y & 0xFFFF));
      a3 += bf2f((unsigned short)(v.y >> 16));
    }
  }
  for (; e < cnt; ++e) {
    uint2 v = rows2[(size_t)csr[e] * 64 + lane];
    a0 += bf2f((unsigned short)(v.x & 0xFFFF));
    a1 += bf2f((unsigned short)(v.x >> 16));
    a2 += bf2f((unsigned short)(v.y & 0xFFFF));
    a3 += bf2f((unsigned short)(v.y >> 16));
  }

  float nd = norm_d[node];
  float4 bb = *(const float4*)&b1[4 * lane];
  float o0 = fmaxf(a0 * nd + bb.x, 0.f);
  float o1 = fmaxf(a1 * nd + bb.y, 0.f);
  float o2 = fmaxf(a2 * nd + bb.z, 0.f);
  float o3 = fmaxf(a3 * nd + bb.w, 0.f);
  out[(size_t)node * 64 + lane] = make_uint2(pack2bf(o0, o1), pack2bf(o2, o3));
}

// ---------------- MFMA GEMM2 ----------------
__global__ __launch_bounds__(256) void k_mm2(const unsigned short* __restrict__ h2b,
                                             const unsigned short* __restrict__ Wp,
                                             const float* __restrict__ norm_s,
                                             unsigned short* __restrict__ out) {
  __shared__ unsigned short sA[64 * 256];
  int tid = threadIdx.x;
  int r0 = blockIdx.x * 64;
  #pragma unroll
  for (int it = 0; it < 8; ++it) {
    int idx = it * 256 + tid;
    int r = idx >> 5, kb = idx & 31;
    uint4 v = make_uint4(0, 0, 0, 0);
    int row = r0 + r;
    if (row < N_NODES) v = *(const uint4*)(h2b + (size_t)row * 256 + kb * 8);
    *(uint4*)&sA[r * 256 + ((kb ^ (r & 7)) << 3)] = v;
  }
  __syncthreads();

  int w = tid >> 6, lane = tid & 63;
  const short8* W8 = (const short8*)Wp;
  f32x4 acc[3];
  #pragma unroll
  for (int j = 0; j < 3; ++j) acc[j] = (f32x4){0.f, 0.f, 0.f, 0.f};

  #pragma unroll
  for (int kt = 0; kt < 8; ++kt) {
    int r = w * 16 + (lane & 15);
    int kb = kt * 4 + (lane >> 4);
    short8 a = *(const short8*)&sA[r * 256 + ((kb ^ (r & 7)) << 3)];
    #pragma unroll
    for (int jb = 0; jb < 3; ++jb) {
      short8 b = W8[(kt * 3 + jb) * 64 + lane];
      acc[jb] = __builtin_amdgcn_mfma_f32_16x16x32_bf16(a, b, acc[jb], 0, 0, 0);
    }
  }

  #pragma unroll
  for (int rr = 0; rr < 4; ++rr) {
    int row = r0 + w * 16 + (lane >> 4) * 4 + rr;
    if (row < N_NODES) {
      float ns = norm_s[row];
      #pragma unroll
      for (int jb = 0; jb < 3; ++jb) {
        int col = jb * 16 + (lane & 15);
        if (col < N_CLASSES) out[(size_t)row * N_CLASSES + col] = f2bf(acc[jb][rr] * ns);
      }
    }
  }
}

// ---------------- aggregation layer 2 (padded CSR, 3 edge-slots x 20 lanes) ----------------
__global__ __launch_bounds__(256) void k_agg2(const unsigned int* __restrict__ rows, // hw2b
                                              const int* __restrict__ cursor,
                                              const int* __restrict__ csr_pad,
                                              const float* __restrict__ norm_d,
                                              const float* __restrict__ b2,
                                              float* __restrict__ out) {
  int tid = threadIdx.x;
  int w = tid >> 6, lane = tid & 63;
  int node = blockIdx.x * 4 + w;
  int slot = lane / 20, fl = lane % 20; // slot 3 idle
  int cnt = __builtin_amdgcn_readfirstlane(cursor[node]);
  const int* csr = csr_pad + (size_t)node * SLOT;

  float a0 = 0.f, a1 = 0.f;
  if (slot < 3) {
    for (int e = slot; e < cnt; e += 3) {
      int s = csr[e];
      unsigned int v = rows[(size_t)s * 20 + fl];
      a0 += bf2f((unsigned short)(v & 0xFFFF));
      a1 += bf2f((unsigned short)(v >> 16));
    }
  }
  float p0 = __shfl(a0, lane + 20), p1 = __shfl(a1, lane + 20);
  float q0 = __shfl(a0, lane + 40), q1 = __shfl(a1, lane + 40);
  if (slot == 0) {
    a0 += p0 + q0; a1 += p1 + q1;
    float nd = norm_d[node];
    float o0 = a0 * nd + b2[2 * fl];
    float o1 = a1 * nd + b2[2 * fl + 1];
    *(float2*)&out[(size_t)node * N_CLASSES + 2 * fl] = make_float2(o0, o1);
  }
}

extern "C" void kernel_launch(void* const* d_in, const int* in_sizes, int n_in,
                              void* d_out, int out_size, void* d_ws, size_t ws_size,
                              hipStream_t stream) {
  const int*   feats = (const int*)d_in[0];
  const int*   src   = (const int*)d_in[1];
  const int*   dst   = (const int*)d_in[2];
  const float* emb   = (const float*)d_in[3];
  const float* W1    = (const float*)d_in[4];
  const float* b1    = (const float*)d_in[5];
  const float* W2    = (const float*)d_in[6];
  const float* b2    = (const float*)d_in[7];
  float* out = (float*)d_out;

  char* base = (char*)d_ws;
  size_t off = 0;
  auto alloc = [&](size_t bytes) -> char* {
    char* p = base + off;
    off += (bytes + 255) & ~(size_t)255;
    return p;
  };
  unsigned short* hb      = (unsigned short*)alloc((size_t)N_NODES * IN_FEATS * 2);  // h bf16; reused as h2b
  unsigned short* msgb    = (unsigned short*)alloc((size_t)N_NODES * N_HIDDEN * 2);
  unsigned short* hw2b    = (unsigned short*)alloc((size_t)N_NODES * N_CLASSES * 2);
  unsigned short* emb_b   = (unsigned short*)alloc((size_t)N_TOKENS * EMB_DIM * 2);
  unsigned short* Wp1     = (unsigned short*)alloc((size_t)8 * 16 * 64 * 8 * 2);
  unsigned short* Wp2     = (unsigned short*)alloc((size_t)8 * 3 * 64 * 8 * 2);
  int*   gcnt    = (int*)alloc((size_t)512 * 4);           // gcntD | gcntS
  int*   gcntD   = gcnt;
  int*   gcntS   = gcnt + 256;
  int*   cursor  = (int*)alloc((size_t)N_NODES * 4);
  int*   deg_out = (int*)alloc((size_t)N_NODES * 4);
  float* norm_s  = (float*)alloc((size_t)N_NODES * 4);
  float* norm_d  = (float*)alloc((size_t)N_NODES * 4);
  unsigned int*  dbin = (unsigned int*)alloc((size_t)NBIN * BINCAP * 4);  // 3.6MB
  unsigned char* sbin = (unsigned char*)alloc((size_t)NBIN * BINCAP);     // 0.9MB
  int*   csr_pad = (int*)alloc((size_t)N_NODES * SLOT * 4); // 12.8MB

  hipMemsetAsync(gcnt, 0, 512 * 4, stream);

  int nb = (N_NODES + 255) / 256;
  k_emb2bf<<<2048, 256, 0, stream>>>(emb, emb_b);
  k_packW1<<<32, 256, 0, stream>>>(W1, Wp1);
  k_packW2<<<6, 256, 0, stream>>>(W2, Wp2);
  k_binA<<<N_EDGES / EPB, 256, 0, stream>>>(src, dst, gcntD, gcntS, dbin, sbin);
  k_binB<<<NBIN, 256, 0, stream>>>(dbin, gcntD, cursor, csr_pad);
  k_degout<<<NBIN, 256, 0, stream>>>(sbin, gcntS, deg_out);
  k_norm<<<nb, 256, 0, stream>>>(deg_out, cursor, norm_s, norm_d);

  int gemm_blocks = (N_NODES + 63) / 64; // 782
  k_embed<<<N_NODES / 4, 256, 0, stream>>>(feats, (const uint2*)emb_b, (uint2*)hb);
  k_mm1<<<gemm_blocks, 256, 0, stream>>>(hb, Wp1, norm_s, msgb);
  k_agg1<<<N_NODES / 4, 256, 0, stream>>>((const uint2*)msgb, cursor, csr_pad, norm_d, b1, (uint2*)hb);
  k_mm2<<<gemm_blocks, 256, 0, stream>>>(hb, Wp2, norm_s, hw2b);
  k_agg2<<<N_NODES / 4, 256, 0, stream>>>((const unsigned int*)hw2b, cursor, csr_pad, norm_d, b2, out);
}

// Round 9
// 225.781 us; speedup vs baseline: 2.5199x; 1.0199x over previous
//
#include <hip/hip_runtime.h>
#include <math.h>

#define N_NODES 50000
#define SEQ_LEN 32
#define EMB_DIM 128
#define IN_FEATS 256
#define N_HIDDEN 256
#define N_CLASSES 40
#define N_EDGES 800000
#define N_TOKENS 100000

#define SLOT 64          // padded-CSR slots per node
#define NBIN 196         // ceil(50000/256) bins of 256 nodes
#define BINCAP 4608      // mean 4096 + 8 sigma
#define EPB 4000         // edges per binA block (200 blocks)

typedef short short8 __attribute__((ext_vector_type(8)));
typedef float f32x4 __attribute__((ext_vector_type(4)));

__device__ __forceinline__ unsigned short f2bf(float x) {
  unsigned int u = __float_as_uint(x);
  unsigned int r = (u + 0x7FFFu + ((u >> 16) & 1u)) >> 16; // RTNE
  return (unsigned short)r;
}
__device__ __forceinline__ float bf2f(unsigned short s) {
  return __uint_as_float((unsigned int)s << 16);
}
__device__ __forceinline__ unsigned int pack2bf(float a, float b) {
  return (unsigned int)f2bf(a) | ((unsigned int)f2bf(b) << 16);
}

// ---------------- fused prep: emb->bf16 | packW1 | packW2 ----------------
__global__ __launch_bounds__(256) void k_prep(const float* __restrict__ emb,
                                              unsigned short* __restrict__ emb_b,
                                              const float* __restrict__ W1,
                                              unsigned short* __restrict__ Wp1,
                                              const float* __restrict__ W2,
                                              unsigned short* __restrict__ Wp2) {
  int b = blockIdx.x, tid = threadIdx.x;
  if (b < 2048) {
    const int total = N_TOKENS * EMB_DIM / 4;
    for (int i = b * 256 + tid; i < total; i += 2048 * 256) {
      float4 v = ((const float4*)emb)[i];
      ushort4 o;
      o.x = f2bf(v.x); o.y = f2bf(v.y); o.z = f2bf(v.z); o.w = f2bf(v.w);
      ((ushort4*)emb_b)[i] = o;
    }
  } else if (b < 2080) {
    int g = (b - 2048) * 256 + tid; // 8192
    int lane = g & 63, jb = (g >> 6) & 15, kt = g >> 10;
    int col = jb * 16 + (lane & 15);
    int kbase = kt * 32 + (lane >> 4) * 8;
    unsigned short* o = Wp1 + (size_t)g * 8;
    #pragma unroll
    for (int e = 0; e < 8; ++e) o[e] = f2bf(W1[(size_t)(kbase + e) * N_HIDDEN + col]);
  } else {
    int g = (b - 2080) * 256 + tid; // 1536
    if (g < 8 * 3 * 64) {
      int lane = g & 63, jb = (g >> 6) % 3, kt = g / (3 * 64);
      int col = jb * 16 + (lane & 15);
      int kbase = kt * 32 + (lane >> 4) * 8;
      unsigned short* o = Wp2 + (size_t)g * 8;
      #pragma unroll
      for (int e = 0; e < 8; ++e)
        o[e] = (col < N_CLASSES) ? f2bf(W2[(size_t)(kbase + e) * N_CLASSES + col]) : (unsigned short)0;
    }
  }
}

// ---------------- binA: LDS-histogram edges into dst-bins + src-bins ----------------
__global__ __launch_bounds__(256) void k_binA(const int* __restrict__ src,
                                              const int* __restrict__ dst,
                                              int* __restrict__ gcntD,
                                              int* __restrict__ gcntS,
                                              unsigned int* __restrict__ dbin,
                                              unsigned char* __restrict__ sbin) {
  __shared__ int cntD[NBIN], cntS[NBIN], baseD[NBIN], baseS[NBIN];
  int tid = threadIdx.x;
  if (tid < NBIN) { cntD[tid] = 0; cntS[tid] = 0; }
  __syncthreads();
  int e0 = blockIdx.x * EPB;
  for (int j = tid; j < EPB; j += 256) {
    int d = dst[e0 + j], s = src[e0 + j];
    atomicAdd(&cntD[d >> 8], 1);
    atomicAdd(&cntS[s >> 8], 1);
  }
  __syncthreads();
  if (tid < NBIN) {
    baseD[tid] = atomicAdd(&gcntD[tid], cntD[tid]);
    baseS[tid] = atomicAdd(&gcntS[tid], cntS[tid]);
    cntD[tid] = 0;
    cntS[tid] = 0;
  }
  __syncthreads();
  for (int j = tid; j < EPB; j += 256) {
    int d = dst[e0 + j], s = src[e0 + j];
    int bd = d >> 8, bs = s >> 8;
    int od = atomicAdd(&cntD[bd], 1);
    int pd = baseD[bd] + od;
    if (pd < BINCAP) dbin[(size_t)bd * BINCAP + pd] = ((unsigned int)s << 8) | (unsigned int)(d & 255);
    int os = atomicAdd(&cntS[bs], 1);
    int ps = baseS[bs] + os;
    if (ps < BINCAP) sbin[(size_t)bs * BINCAP + ps] = (unsigned char)(s & 255);
  }
}

// ---------------- binB: per-bin CSR build (no global atomics) ----------------
__global__ __launch_bounds__(256) void k_binB(const unsigned int* __restrict__ dbin,
                                              const int* __restrict__ gcntD,
                                              int* __restrict__ cursor,
                                              int* __restrict__ csr_pad) {
  __shared__ int cnt[256];
  int tid = threadIdx.x, b = blockIdx.x;
  cnt[tid] = 0;
  __syncthreads();
  int n = min(gcntD[b], BINCAP);
  const unsigned int* bb = dbin + (size_t)b * BINCAP;
  for (int j = tid; j < n; j += 256) {
    unsigned int e = bb[j];
    int lo = e & 255;
    int slot = atomicAdd(&cnt[lo], 1);
    if (slot < SLOT) csr_pad[(size_t)(b * 256 + lo) * SLOT + slot] = (int)(e >> 8);
  }
  __syncthreads();
  int node = b * 256 + tid;
  if (node < N_NODES) cursor[node] = min(cnt[tid], SLOT);
}

// ---------------- degout + norms (after binB; cursor ready) ----------------
__global__ __launch_bounds__(256) void k_degoutnorm(const unsigned char* __restrict__ sbin,
                                                    const int* __restrict__ gcntS,
                                                    const int* __restrict__ cursor,
                                                    float* __restrict__ norm_s,
                                                    float* __restrict__ norm_d) {
  __shared__ int cnt[256];
  int tid = threadIdx.x, b = blockIdx.x;
  cnt[tid] = 0;
  __syncthreads();
  int n = min(gcntS[b], BINCAP);
  const unsigned char* bb = sbin + (size_t)b * BINCAP;
  for (int j = tid; j < n; j += 256) atomicAdd(&cnt[bb[j]], 1);
  __syncthreads();
  int node = b * 256 + tid;
  if (node < N_NODES) {
    norm_s[node] = 1.0f / sqrtf((float)max(cnt[tid], 1));
    norm_d[node] = 1.0f / sqrtf((float)max(cursor[node], 1));
  }
}

// ---------------- embedding + pooling: 1 wave = 1 node, uint4/lane ----------------
// 16 lanes cover a 256B token row; 4 quarter-groups process 4 tokens/iter, 8 iters.
__global__ __launch_bounds__(256) void k_embed(const int* __restrict__ feats,
                                               const uint4* __restrict__ rows4, // emb_b (16 uint4/row)
                                               uint4* __restrict__ h4) {       // hb (32 uint4/row)
  int tid = threadIdx.x;
  int w = tid >> 6, lane = tid & 63;
  int node = blockIdx.x * 4 + w;
  int lq = lane & 15, qg = lane >> 4;
  int laneL = lane & 31;

  int tok0 = feats[(size_t)node * SEQ_LEN + laneL];
  unsigned long long m = __ballot(tok0 != 0);
  int cnt = (int)__popcll(m & 0xFFFFFFFFull);
  float inv = 1.0f / (float)max(cnt, 1);

  float s0 = 0.f, s1 = 0.f, s2 = 0.f, s3 = 0.f, s4 = 0.f, s5 = 0.f, s6 = 0.f, s7 = 0.f;
  float m0 = -INFINITY, m1 = -INFINITY, m2 = -INFINITY, m3 = -INFINITY;
  float m4 = -INFINITY, m5 = -INFINITY, m6 = -INFINITY, m7 = -INFINITY;
  #pragma unroll
  for (int t = 0; t < 8; ++t) {
    int tok = __shfl(tok0, t * 4 + qg);
    uint4 v = make_uint4(0u, 0u, 0u, 0u);
    if (tok) v = rows4[(size_t)tok * 16 + lq];
    float f0 = bf2f((unsigned short)(v.x & 0xFFFF)), f1 = bf2f((unsigned short)(v.x >> 16));
    float f2 = bf2f((unsigned short)(v.y & 0xFFFF)), f3 = bf2f((unsigned short)(v.y >> 16));
    float f4 = bf2f((unsigned short)(v.z & 0xFFFF)), f5 = bf2f((unsigned short)(v.z >> 16));
    float f6 = bf2f((unsigned short)(v.w & 0xFFFF)), f7 = bf2f((unsigned short)(v.w >> 16));
    s0 += f0; s1 += f1; s2 += f2; s3 += f3; s4 += f4; s5 += f5; s6 += f6; s7 += f7;
    m0 = fmaxf(m0, f0); m1 = fmaxf(m1, f1); m2 = fmaxf(m2, f2); m3 = fmaxf(m3, f3);
    m4 = fmaxf(m4, f4); m5 = fmaxf(m5, f5); m6 = fmaxf(m6, f6); m7 = fmaxf(m7, f7);
  }
  #pragma unroll
  for (int mask = 16; mask <= 32; mask <<= 1) {
    s0 += __shfl_xor(s0, mask); s1 += __shfl_xor(s1, mask);
    s2 += __shfl_xor(s2, mask); s3 += __shfl_xor(s3, mask);
    s4 += __shfl_xor(s4, mask); s5 += __shfl_xor(s5, mask);
    s6 += __shfl_xor(s6, mask); s7 += __shfl_xor(s7, mask);
    m0 = fmaxf(m0, __shfl_xor(m0, mask)); m1 = fmaxf(m1, __shfl_xor(m1, mask));
    m2 = fmaxf(m2, __shfl_xor(m2, mask)); m3 = fmaxf(m3, __shfl_xor(m3, mask));
    m4 = fmaxf(m4, __shfl_xor(m4, mask)); m5 = fmaxf(m5, __shfl_xor(m5, mask));
    m6 = fmaxf(m6, __shfl_xor(m6, mask)); m7 = fmaxf(m7, __shfl_xor(m7, mask));
  }
  if (qg == 0) {
    uint4* hv = h4 + (size_t)node * 32;
    hv[lq] = make_uint4(pack2bf(s0 * inv, s1 * inv), pack2bf(s2 * inv, s3 * inv),
                        pack2bf(s4 * inv, s5 * inv), pack2bf(s6 * inv, s7 * inv));
    hv[16 + lq] = make_uint4(pack2bf(m0, m1), pack2bf(m2, m3),
                             pack2bf(m4, m5), pack2bf(m6, m7));
  }
}

// ---------------- MFMA GEMM1 ----------------
__global__ __launch_bounds__(256) void k_mm1(const unsigned short* __restrict__ hb,
                                             const unsigned short* __restrict__ Wp,
                                             const float* __restrict__ norm_s,
                                             unsigned short* __restrict__ out) {
  __shared__ unsigned short sA[64 * 256];
  int tid = threadIdx.x;
  int r0 = blockIdx.x * 64;
  #pragma unroll
  for (int it = 0; it < 8; ++it) {
    int idx = it * 256 + tid;
    int r = idx >> 5, kb = idx & 31;
    uint4 v = make_uint4(0, 0, 0, 0);
    int row = r0 + r;
    if (row < N_NODES) v = *(const uint4*)(hb + (size_t)row * 256 + kb * 8);
    *(uint4*)&sA[r * 256 + ((kb ^ (r & 7)) << 3)] = v;
  }
  __syncthreads();

  int w = tid >> 6, lane = tid & 63;
  const short8* W8 = (const short8*)Wp;
  f32x4 acc[4][4];
  #pragma unroll
  for (int i = 0; i < 4; ++i)
    #pragma unroll
    for (int j = 0; j < 4; ++j) acc[i][j] = (f32x4){0.f, 0.f, 0.f, 0.f};

  #pragma unroll
  for (int kt = 0; kt < 8; ++kt) {
    short8 a[4], b[4];
    int kb = kt * 4 + (lane >> 4);
    #pragma unroll
    for (int ri = 0; ri < 4; ++ri) {
      int r = ri * 16 + (lane & 15);
      a[ri] = *(const short8*)&sA[r * 256 + ((kb ^ (r & 7)) << 3)];
    }
    #pragma unroll
    for (int jb = 0; jb < 4; ++jb) b[jb] = W8[(kt * 16 + w * 4 + jb) * 64 + lane];
    #pragma unroll
    for (int ri = 0; ri < 4; ++ri)
      #pragma unroll
      for (int jb = 0; jb < 4; ++jb)
        acc[ri][jb] = __builtin_amdgcn_mfma_f32_16x16x32_bf16(a[ri], b[jb], acc[ri][jb], 0, 0, 0);
  }

  #pragma unroll
  for (int ri = 0; ri < 4; ++ri) {
    #pragma unroll
    for (int rr = 0; rr < 4; ++rr) {
      int row = r0 + ri * 16 + (lane >> 4) * 4 + rr;
      if (row < N_NODES) {
        float ns = norm_s[row];
        #pragma unroll
        for (int jb = 0; jb < 4; ++jb) {
          int col = w * 64 + jb * 16 + (lane & 15);
          out[(size_t)row * 256 + col] = f2bf(acc[ri][jb][rr] * ns);
        }
      }
    }
  }
}

// ---------------- aggregation layer 1: 1 wave = 1 node, uint4/lane ----------------
// 32 lanes cover a 512B msg row; halves process 2 edges concurrently.
__global__ __launch_bounds__(256) void k_agg1(const uint4* __restrict__ rows4, // msgb (32 uint4/row)
                                              const int* __restrict__ cursor,
                                              const int* __restrict__ csr_pad,
                                              const float* __restrict__ norm_d,
                                              const float* __restrict__ b1,
                                              uint4* __restrict__ out4) {
  int tid = threadIdx.x;
  int w = tid >> 6, lane = tid & 63;
  int node = blockIdx.x * 4 + w;
  int cnt = __builtin_amdgcn_readfirstlane(cursor[node]);
  const int* csr = csr_pad + (size_t)node * SLOT;
  int half = lane >> 5, lq = lane & 31;

  float a0 = 0.f, a1 = 0.f, a2 = 0.f, a3 = 0.f, a4 = 0.f, a5 = 0.f, a6 = 0.f, a7 = 0.f;
  int e = 0;
  for (; e + 8 <= cnt; e += 8) {
    int s0 = csr[e + 0 + half], s1 = csr[e + 2 + half];
    int s2 = csr[e + 4 + half], s3 = csr[e + 6 + half];
    uint4 v0 = rows4[(size_t)s0 * 32 + lq];
    uint4 v1 = rows4[(size_t)s1 * 32 + lq];
    uint4 v2 = rows4[(size_t)s2 * 32 + lq];
    uint4 v3 = rows4[(size_t)s3 * 32 + lq];
    #pragma unroll
    for (int i = 0; i < 4; ++i) {
      uint4 v = (i == 0) ? v0 : (i == 1) ? v1 : (i == 2) ? v2 : v3;
      a0 += bf2f((unsigned short)(v.x & 0xFFFF)); a1 += bf2f((unsigned short)(v.x >> 16));
      a2 += bf2f((unsigned short)(v.y & 0xFFFF)); a3 += bf2f((unsigned short)(v.y >> 16));
      a4 += bf2f((unsigned short)(v.z & 0xFFFF)); a5 += bf2f((unsigned short)(v.z >> 16));
      a6 += bf2f((unsigned short)(v.w & 0xFFFF)); a7 += bf2f((unsigned short)(v.w >> 16));
    }
  }
  for (; e + 2 <= cnt; e += 2) {
    int s = csr[e + half];
    uint4 v = rows4[(size_t)s * 32 + lq];
    a0 += bf2f((unsigned short)(v.x & 0xFFFF)); a1 += bf2f((unsigned short)(v.x >> 16));
    a2 += bf2f((unsigned short)(v.y & 0xFFFF)); a3 += bf2f((unsigned short)(v.y >> 16));
    a4 += bf2f((unsigned short)(v.z & 0xFFFF)); a5 += bf2f((unsigned short)(v.z >> 16));
    a6 += bf2f((unsigned short)(v.w & 0xFFFF)); a7 += bf2f((unsigned short)(v.w >> 16));
  }
  if (e < cnt) {
    uint4 v = make_uint4(0u, 0u, 0u, 0u);
    if (half == 0) v = rows4[(size_t)csr[e] * 32 + lq];
    a0 += bf2f((unsigned short)(v.x & 0xFFFF)); a1 += bf2f((unsigned short)(v.x >> 16));
    a2 += bf2f((unsigned short)(v.y & 0xFFFF)); a3 += bf2f((unsigned short)(v.y >> 16));
    a4 += bf2f((unsigned short)(v.z & 0xFFFF)); a5 += bf2f((unsigned short)(v.z >> 16));
    a6 += bf2f((unsigned short)(v.w & 0xFFFF)); a7 += bf2f((unsigned short)(v.w >> 16));
  }
  a0 += __shfl_xor(a0, 32); a1 += __shfl_xor(a1, 32);
  a2 += __shfl_xor(a2, 32); a3 += __shfl_xor(a3, 32);
  a4 += __shfl_xor(a4, 32); a5 += __shfl_xor(a5, 32);
  a6 += __shfl_xor(a6, 32); a7 += __shfl_xor(a7, 32);

  if (half == 0) {
    float nd = norm_d[node];
    float4 bb0 = *(const float4*)&b1[8 * lq];
    float4 bb1 = *(const float4*)&b1[8 * lq + 4];
    float o0 = fmaxf(a0 * nd + bb0.x, 0.f), o1 = fmaxf(a1 * nd + bb0.y, 0.f);
    float o2 = fmaxf(a2 * nd + bb0.z, 0.f), o3 = fmaxf(a3 * nd + bb0.w, 0.f);
    float o4 = fmaxf(a4 * nd + bb1.x, 0.f), o5 = fmaxf(a5 * nd + bb1.y, 0.f);
    float o6 = fmaxf(a6 * nd + bb1.z, 0.f), o7 = fmaxf(a7 * nd + bb1.w, 0.f);
    out4[(size_t)node * 32 + lq] = make_uint4(pack2bf(o0, o1), pack2bf(o2, o3),
                                              pack2bf(o4, o5), pack2bf(o6, o7));
  }
}

// ---------------- MFMA GEMM2 ----------------
__global__ __launch_bounds__(256) void k_mm2(const unsigned short* __restrict__ h2b,
                                             const unsigned short* __restrict__ Wp,
                                             const float* __restrict__ norm_s,
                                             unsigned short* __restrict__ out) {
  __shared__ unsigned short sA[64 * 256];
  int tid = threadIdx.x;
  int r0 = blockIdx.x * 64;
  #pragma unroll
  for (int it = 0; it < 8; ++it) {
    int idx = it * 256 + tid;
    int r = idx >> 5, kb = idx & 31;
    uint4 v = make_uint4(0, 0, 0, 0);
    int row = r0 + r;
    if (row < N_NODES) v = *(const uint4*)(h2b + (size_t)row * 256 + kb * 8);
    *(uint4*)&sA[r * 256 + ((kb ^ (r & 7)) << 3)] = v;
  }
  __syncthreads();

  int w = tid >> 6, lane = tid & 63;
  const short8* W8 = (const short8*)Wp;
  f32x4 acc[3];
  #pragma unroll
  for (int j = 0; j < 3; ++j) acc[j] = (f32x4){0.f, 0.f, 0.f, 0.f};

  #pragma unroll
  for (int kt = 0; kt < 8; ++kt) {
    int r = w * 16 + (lane & 15);
    int kb = kt * 4 + (lane >> 4);
    short8 a = *(const short8*)&sA[r * 256 + ((kb ^ (r & 7)) << 3)];
    #pragma unroll
    for (int jb = 0; jb < 3; ++jb) {
      short8 b = W8[(kt * 3 + jb) * 64 + lane];
      acc[jb] = __builtin_amdgcn_mfma_f32_16x16x32_bf16(a, b, acc[jb], 0, 0, 0);
    }
  }

  #pragma unroll
  for (int rr = 0; rr < 4; ++rr) {
    int row = r0 + w * 16 + (lane >> 4) * 4 + rr;
    if (row < N_NODES) {
      float ns = norm_s[row];
      #pragma unroll
      for (int jb = 0; jb < 3; ++jb) {
        int col = jb * 16 + (lane & 15);
        if (col < N_CLASSES) out[(size_t)row * N_CLASSES + col] = f2bf(acc[jb][rr] * ns);
      }
    }
  }
}

// ---------------- aggregation layer 2 (padded CSR, 3 edge-slots x 20 lanes) ----------------
__global__ __launch_bounds__(256) void k_agg2(const unsigned int* __restrict__ rows, // hw2b
                                              const int* __restrict__ cursor,
                                              const int* __restrict__ csr_pad,
                                              const float* __restrict__ norm_d,
                                              const float* __restrict__ b2,
                                              float* __restrict__ out) {
  int tid = threadIdx.x;
  int w = tid >> 6, lane = tid & 63;
  int node = blockIdx.x * 4 + w;
  int slot = lane / 20, fl = lane % 20; // slot 3 idle
  int cnt = __builtin_amdgcn_readfirstlane(cursor[node]);
  const int* csr = csr_pad + (size_t)node * SLOT;

  float a0 = 0.f, a1 = 0.f;
  if (slot < 3) {
    for (int e = slot; e < cnt; e += 3) {
      int s = csr[e];
      unsigned int v = rows[(size_t)s * 20 + fl];
      a0 += bf2f((unsigned short)(v & 0xFFFF));
      a1 += bf2f((unsigned short)(v >> 16));
    }
  }
  float p0 = __shfl(a0, lane + 20), p1 = __shfl(a1, lane + 20);
  float q0 = __shfl(a0, lane + 40), q1 = __shfl(a1, lane + 40);
  if (slot == 0) {
    a0 += p0 + q0; a1 += p1 + q1;
    float nd = norm_d[node];
    float o0 = a0 * nd + b2[2 * fl];
    float o1 = a1 * nd + b2[2 * fl + 1];
    *(float2*)&out[(size_t)node * N_CLASSES + 2 * fl] = make_float2(o0, o1);
  }
}

extern "C" void kernel_launch(void* const* d_in, const int* in_sizes, int n_in,
                              void* d_out, int out_size, void* d_ws, size_t ws_size,
                              hipStream_t stream) {
  const int*   feats = (const int*)d_in[0];
  const int*   src   = (const int*)d_in[1];
  const int*   dst   = (const int*)d_in[2];
  const float* emb   = (const float*)d_in[3];
  const float* W1    = (const float*)d_in[4];
  const float* b1    = (const float*)d_in[5];
  const float* W2    = (const float*)d_in[6];
  const float* b2    = (const float*)d_in[7];
  float* out = (float*)d_out;

  char* base = (char*)d_ws;
  size_t off = 0;
  auto alloc = [&](size_t bytes) -> char* {
    char* p = base + off;
    off += (bytes + 255) & ~(size_t)255;
    return p;
  };
  unsigned short* hb      = (unsigned short*)alloc((size_t)N_NODES * IN_FEATS * 2);  // h bf16; reused as h2b
  unsigned short* msgb    = (unsigned short*)alloc((size_t)N_NODES * N_HIDDEN * 2);
  unsigned short* hw2b    = (unsigned short*)alloc((size_t)N_NODES * N_CLASSES * 2);
  unsigned short* emb_b   = (unsigned short*)alloc((size_t)N_TOKENS * EMB_DIM * 2);
  unsigned short* Wp1     = (unsigned short*)alloc((size_t)8 * 16 * 64 * 8 * 2);
  unsigned short* Wp2     = (unsigned short*)alloc((size_t)8 * 3 * 64 * 8 * 2);
  int*   gcnt    = (int*)alloc((size_t)512 * 4);           // gcntD | gcntS
  int*   gcntD   = gcnt;
  int*   gcntS   = gcnt + 256;
  int*   cursor  = (int*)alloc((size_t)N_NODES * 4);
  float* norm_s  = (float*)alloc((size_t)N_NODES * 4);
  float* norm_d  = (float*)alloc((size_t)N_NODES * 4);
  unsigned int*  dbin = (unsigned int*)alloc((size_t)NBIN * BINCAP * 4);  // 3.6MB
  unsigned char* sbin = (unsigned char*)alloc((size_t)NBIN * BINCAP);     // 0.9MB
  int*   csr_pad = (int*)alloc((size_t)N_NODES * SLOT * 4); // 12.8MB

  hipMemsetAsync(gcnt, 0, 512 * 4, stream);

  k_prep<<<2086, 256, 0, stream>>>(emb, emb_b, W1, Wp1, W2, Wp2);
  k_binA<<<N_EDGES / EPB, 256, 0, stream>>>(src, dst, gcntD, gcntS, dbin, sbin);
  k_binB<<<NBIN, 256, 0, stream>>>(dbin, gcntD, cursor, csr_pad);
  k_degoutnorm<<<NBIN, 256, 0, stream>>>(sbin, gcntS, cursor, norm_s, norm_d);

  int gemm_blocks = (N_NODES + 63) / 64; // 782
  k_embed<<<N_NODES / 4, 256, 0, stream>>>(feats, (const uint4*)emb_b, (uint4*)hb);
  k_mm1<<<gemm_blocks, 256, 0, stream>>>(hb, Wp1, norm_s, msgb);
  k_agg1<<<N_NODES / 4, 256, 0, stream>>>((const uint4*)msgb, cursor, csr_pad, norm_d, b1, (uint4*)hb);
  k_mm2<<<gemm_blocks, 256, 0, stream>>>(hb, Wp2, norm_s, hw2b);
  k_agg2<<<N_NODES / 4, 256, 0, stream>>>((const unsigned int*)hw2b, cursor, csr_pad, norm_d, b2, out);
}